// Round 10
// baseline (16322.717 us; speedup 1.0000x reference)
//
#include <hip/hip_runtime.h>
#include <stdint.h>

// LBG vector quantization, bit-faithful port of the JAX ref.
// Round 10: persistent kernel via NORMAL launch (graph-safe) + hand-rolled
// sense-reversing grid barrier (device-scope atomics + threadfence).
// Co-residency by construction: 512 blocks, LDS 49792 B (3/CU), VGPR<=256
// via launch_bounds(256,2) (>=2/CU) => all 512 resident.
// estep for CURR>=64 = R6's 4p x 8c / 64-cw-panel variant (best measured;
// d2 chain bitwise-identical to R8). All other phases verbatim R8 =>
// bit-identical trajectory (absmax 0.4985352).

#define NPTS 131072
#define DIMS 64
#define KCB  256
#define NBLKP 512

struct LbgState { float dist; float prev; unsigned int done; unsigned int k0, k1; unsigned int pad; };
struct GBar { unsigned int cnt; unsigned int gen; };

__device__ __forceinline__ uint32_t rotl32(uint32_t v, int n){ return (v<<n)|(v>>(32-n)); }

// Threefry-2x32, 20 rounds (matches jax._src.prng.threefry2x32)
__device__ __forceinline__ void tf2x32(uint32_t k0, uint32_t k1, uint32_t x0, uint32_t x1,
                                       uint32_t& o0, uint32_t& o1){
  uint32_t ks2 = k0 ^ k1 ^ 0x1BD11BDAu;
  x0 += k0; x1 += k1;
  #define TFR(r) { x0 += x1; x1 = rotl32(x1, r); x1 ^= x0; }
  TFR(13) TFR(15) TFR(26) TFR(6)
  x0 += k1; x1 += ks2 + 1u;
  TFR(17) TFR(29) TFR(16) TFR(24)
  x0 += ks2; x1 += k0 + 2u;
  TFR(13) TFR(15) TFR(26) TFR(6)
  x0 += k0; x1 += k1 + 3u;
  TFR(17) TFR(29) TFR(16) TFR(24)
  x0 += k1; x1 += ks2 + 4u;
  TFR(13) TFR(15) TFR(26) TFR(6)
  x0 += ks2; x1 += k0 + 5u;
  #undef TFR
  o0 = x0; o1 = x1;
}

// XLA ErfInv (f32, Giles polynomial)
__device__ __forceinline__ float xla_erfinv_f32(float x){
  float w = -log1pf(-x*x);
  float p;
  if (w < 5.0f){
    w = w - 2.5f;
    p = 2.81022636e-08f;
    p = fmaf(p, w, 3.43273939e-07f);
    p = fmaf(p, w, -3.5233877e-06f);
    p = fmaf(p, w, -4.39150654e-06f);
    p = fmaf(p, w, 0.00021858087f);
    p = fmaf(p, w, -0.00125372503f);
    p = fmaf(p, w, -0.00417768164f);
    p = fmaf(p, w, 0.246640727f);
    p = fmaf(p, w, 1.50140941f);
  } else {
    w = sqrtf(w) - 3.0f;
    p = -0.000200214257f;
    p = fmaf(p, w, 0.000100950558f);
    p = fmaf(p, w, 0.00134934322f);
    p = fmaf(p, w, -0.00367342844f);
    p = fmaf(p, w, 0.00573950773f);
    p = fmaf(p, w, -0.0076224613f);
    p = fmaf(p, w, 0.00943887047f);
    p = fmaf(p, w, 1.00167406f);
    p = fmaf(p, w, 2.83297682f);
  }
  return p * x;
}

__device__ __forceinline__ float jax_normal_elem(uint32_t k0, uint32_t k1, uint32_t j){
  uint32_t o0, o1; tf2x32(k0, k1, 0u, j, o0, o1);
  uint32_t bits = o0 ^ o1;
  uint32_t fb = (bits >> 9) | 0x3f800000u;
  float f = __uint_as_float(fb) - 1.0f;
  const float lo = -0.99999994f;
  float u = f * 2.0f + lo;
  u = fmaxf(lo, u);
  return 1.41421356f * xla_erfinv_f32(u);
}

// ---- sense-reversing grid barrier (device scope). All NBLKP blocks must call. ----
__device__ __forceinline__ void grid_sync(GBar* b){
  __syncthreads();
  if (threadIdx.x == 0){
    __threadfence();                                           // release prior writes
    unsigned int g = __hip_atomic_load(&b->gen, __ATOMIC_RELAXED, __HIP_MEMORY_SCOPE_AGENT);
    unsigned int a = __hip_atomic_fetch_add(&b->cnt, 1u, __ATOMIC_ACQ_REL, __HIP_MEMORY_SCOPE_AGENT);
    if (a == (unsigned)(NBLKP - 1)){
      __hip_atomic_store(&b->cnt, 0u, __ATOMIC_RELAXED, __HIP_MEMORY_SCOPE_AGENT);
      __hip_atomic_store(&b->gen, g + 1u, __ATOMIC_RELEASE, __HIP_MEMORY_SCOPE_AGENT);
    } else {
      while (__hip_atomic_load(&b->gen, __ATOMIC_ACQUIRE, __HIP_MEMORY_SCOPE_AGENT) == g)
        __builtin_amdgcn_s_sleep(2);
    }
    __threadfence();                                           // invalidate for later plain loads
  }
  __syncthreads();
}

// ---- shared-memory overlays (union; max = SmemGemm 49792 B -> 3 blocks/CU) ----
struct SmemMean   { double part[256]; float stage[16*64]; };
struct SmemGemm   { float4 xs[16*128]; float4 cbs[64*16]; float sxx[128]; unsigned char sbidx[128]; };
struct SmemGather { long long sacc[4*64]; unsigned int scw[4]; };
struct SmemCtl    { uint32_t kr0s, kr1s, sub0, sub1; int s_stop, s_m, s_cnt;
                    unsigned int sdone; float cm[64]; int redv[256]; int redi[256]; };

// ---- split phase ----
__device__ void do_split(float* __restrict__ cb, float* __restrict__ cnorm,
                         unsigned long long* __restrict__ sums,
                         unsigned int* __restrict__ ndata,
                         unsigned long long* __restrict__ distacc,
                         LbgState* __restrict__ st, int curr, int split, int t, char* sm){
  SmemCtl* S = (SmemCtl*)sm;
  if (t == 0){
    uint32_t ks0, ks1, a0, a1, b0, b1;
    tf2x32(0u, 42u, 0u, (uint32_t)split, ks0, ks1);
    tf2x32(ks0, ks1, 0u, 0u, a0, a1);
    tf2x32(ks0, ks1, 0u, 1u, b0, b1);
    S->kr0s = a0; S->kr1s = a1;
    st->k0 = b0; st->k1 = b1;
    st->prev = st->dist;
    st->done = 0u;
  }
  __syncthreads();
  const uint32_t kr0 = S->kr0s, kr1 = S->kr1s;
  const int n = curr * DIMS;
  for (int e = t; e < n; e += 256){
    int c = e >> 6, d = e & 63;
    float rv = jax_normal_elem(kr0, kr1, (uint32_t)e) * 1e-5f;
    float old = cb[c*DIMS + d];
    cb[(curr + c)*DIMS + d] = old - rv;
    cb[c*DIMS + d]          = old + rv;
  }
  __syncthreads();
  const int c2 = curr * 2;
  for (int c = t; c < c2; c += 256){
    float s = 0.f;
    for (int d = 0; d < DIMS; d++){ float vv = cb[c*DIMS+d]; s += vv*vv; }
    cnorm[c] = s;
  }
  for (int e = t; e < c2*DIMS; e += 256) sums[e] = 0ull;
  for (int c = t; c < c2; c += 256) ndata[c] = 0u;
  if (t == 0) *distacc = 0ull;
}

// ---- mean phase (blocks 0..127), chains bit-identical to R8 ----
__device__ void mean_phase(const float* __restrict__ x, unsigned long long* __restrict__ macc,
                           int bid, int t, char* sm){
  SmemMean* S = (SmemMean*)sm;
  const int d = t & 63;
  const int w = t >> 6;
  const size_t base = (size_t)bid * 1024;
  const int lrow = t >> 4;
  const int lcol = (t & 15) * 4;
  const float4* xg = reinterpret_cast<const float4*>(x);
  float4 nxt = xg[((base + lrow) * DIMS + lcol) >> 2];
  double s = 0.0;
  for (int tt = 0; tt < 64; tt++){
    float4 cur = nxt;
    if (tt < 63)
      nxt = xg[((base + (tt+1)*16 + lrow) * DIMS + lcol) >> 2];
    __syncthreads();
    *reinterpret_cast<float4*>(&S->stage[lrow*DIMS + lcol]) = cur;
    __syncthreads();
    s += (double)S->stage[(w    )*DIMS + d];
    s += (double)S->stage[(w + 4)*DIMS + d];
    s += (double)S->stage[(w + 8)*DIMS + d];
    s += (double)S->stage[(w +12)*DIMS + d];
  }
  S->part[t] = s;
  __syncthreads();
  if (t < 64){
    double tot = S->part[t] + S->part[64+t] + S->part[128+t] + S->part[192+t];
    atomicAdd(&macc[t], (unsigned long long)__double2ll_rn(tot * 1099511627776.0));
  }
  __syncthreads();
}

// ---- E-step small CURR (<=32): one thread per point (512 blocks cover all) ----
template<int CURR>
__device__ void estep_small(const float* __restrict__ x, const float* __restrict__ cb,
                            const float* __restrict__ cnorm, unsigned char* __restrict__ bidx8,
                            unsigned long long* __restrict__ distacc, int bid, int t){
  const int lane = t & 63;
  const int p = bid * 256 + t;
  float xv[DIMS];
  const float4* xp = reinterpret_cast<const float4*>(x + (size_t)p * DIMS);
  #pragma unroll
  for (int i = 0; i < 16; i++){
    float4 v = xp[i];
    xv[4*i+0] = v.x; xv[4*i+1] = v.y; xv[4*i+2] = v.z; xv[4*i+3] = v.w;
  }
  float xx = 0.f;
  #pragma unroll
  for (int d = 0; d < DIMS; d++) xx += xv[d] * xv[d];

  constexpr int NJ = (CURR < 4) ? CURR : 4;
  float best = __builtin_inff();
  int bi = 0;
  for (int j0 = 0; j0 < CURR; j0 += NJ){
    const float* crow = cb + (size_t)j0 * DIMS;
    float acc[NJ];
    #pragma unroll
    for (int k = 0; k < NJ; k++) acc[k] = 0.f;
    #pragma unroll
    for (int d = 0; d < DIMS; d++){
      #pragma unroll
      for (int k = 0; k < NJ; k++)
        acc[k] = fmaf(xv[d], crow[k*DIMS + d], acc[k]);
    }
    #pragma unroll
    for (int k = 0; k < NJ; k++){
      float d2 = (xx - 2.0f*acc[k]) + cnorm[j0 + k];
      if (d2 < best){ best = d2; bi = j0 + k; }
    }
  }
  bidx8[p] = (unsigned char)bi;

  double dd = 0.0;
  const float4* cbv = reinterpret_cast<const float4*>(cb + (size_t)bi * DIMS);
  #pragma unroll
  for (int i = 0; i < 16; i++){
    float4 b = cbv[i];
    float df, sq;
    df = xv[4*i+0] - b.x; sq = df*df; dd += (double)sq;
    df = xv[4*i+1] - b.y; sq = df*df; dd += (double)sq;
    df = xv[4*i+2] - b.z; sq = df*df; dd += (double)sq;
    df = xv[4*i+3] - b.w; sq = df*df; dd += (double)sq;
  }
  for (int off = 32; off > 0; off >>= 1) dd += __shfl_down(dd, off);
  if (lane == 0)
    atomicAdd(distacc, (unsigned long long)__double2ll_rn(dd * 4294967296.0));
}

// ---- E-step CURR>=64: 4p x 8c tile, 64-cw panels (R6 variant, one tile/call) ----
template<int CURR>
__device__ void estep_gt(const float* __restrict__ x, const float* __restrict__ cb,
                         const float* __restrict__ cnorm, unsigned char* __restrict__ bidx8,
                         unsigned long long* __restrict__ distacc, int tile, int t, char* sm){
  SmemGemm* S = (SmemGemm*)sm;
  constexpr int NPANEL = CURR / 64;
  const int pbase = tile * 128;
  {
    const int p = t & 127, h = t >> 7;
    const float4* xg = reinterpret_cast<const float4*>(x) + (size_t)(pbase + p) * 16 + h * 8;
    #pragma unroll
    for (int j = 0; j < 8; j++)
      S->xs[(h*8 + j)*128 + p] = xg[j];
  }
  __syncthreads();
  if (t < 128){
    float xx = 0.f;
    #pragma unroll
    for (int k4 = 0; k4 < 16; k4++){
      float4 v = S->xs[k4*128 + t];
      xx = fmaf(v.x, v.x, xx); xx = fmaf(v.y, v.y, xx);
      xx = fmaf(v.z, v.z, xx); xx = fmaf(v.w, v.w, xx);
    }
    S->sxx[t] = xx;
  }
  __syncthreads();

  const int cg2 = t & 7;
  const int pg = t >> 3;
  float best[4] = {__builtin_inff(), __builtin_inff(), __builtin_inff(), __builtin_inff()};
  int bidx[4] = {0,0,0,0};
  float xxv[4];
  #pragma unroll
  for (int j = 0; j < 4; j++) xxv[j] = S->sxx[pg + 32*j];

  const float4* cbg = reinterpret_cast<const float4*>(cb);
  for (int panel = 0; panel < NPANEL; panel++){
    __syncthreads();
    for (int idx = t; idx < 1024; idx += 256){
      const int cl = idx >> 4, kk = idx & 15;
      S->cbs[cl*16 + (kk ^ (cl >> 3))] = cbg[(size_t)(panel*64 + cl)*16 + kk];
    }
    __syncthreads();

    const int c0 = panel*64 + cg2*8;
    float acc[4][8];
    #pragma unroll
    for (int j = 0; j < 4; j++)
      #pragma unroll
      for (int cj = 0; cj < 8; cj++) acc[j][cj] = 0.f;

    for (int k4 = 0; k4 < 16; k4++){
      float4 xf[4];
      #pragma unroll
      for (int j = 0; j < 4; j++) xf[j] = S->xs[k4*128 + pg + 32*j];
      #pragma unroll
      for (int cj = 0; cj < 8; cj++){
        float4 cf = S->cbs[(cg2*8 + cj)*16 + (k4 ^ cg2)];
        #pragma unroll
        for (int j = 0; j < 4; j++){
          acc[j][cj] = fmaf(xf[j].x, cf.x, acc[j][cj]);
          acc[j][cj] = fmaf(xf[j].y, cf.y, acc[j][cj]);
          acc[j][cj] = fmaf(xf[j].z, cf.z, acc[j][cj]);
          acc[j][cj] = fmaf(xf[j].w, cf.w, acc[j][cj]);
        }
      }
    }
    #pragma unroll
    for (int cj = 0; cj < 8; cj++){
      float cn = cnorm[c0 + cj];
      #pragma unroll
      for (int j = 0; j < 4; j++){
        float d2 = (xxv[j] - 2.0f*acc[j][cj]) + cn;
        if (d2 < best[j]){ best[j] = d2; bidx[j] = c0 + cj; }
      }
    }
  }
  #pragma unroll
  for (int m = 1; m < 8; m <<= 1){
    #pragma unroll
    for (int j = 0; j < 4; j++){
      float ob = __shfl_xor(best[j], m, 64);
      int   oc = __shfl_xor(bidx[j], m, 64);
      if (ob < best[j] || (ob == best[j] && oc < bidx[j])){ best[j] = ob; bidx[j] = oc; }
    }
  }
  if (cg2 == 0){
    #pragma unroll
    for (int j = 0; j < 4; j++) S->sbidx[pg + 32*j] = (unsigned char)bidx[j];
  }
  __syncthreads();
  if (t < 128){
    const int bi = (int)S->sbidx[t];
    bidx8[pbase + t] = (unsigned char)bi;
    const float4* cbv = cbg + (size_t)bi * 16;
    double dd = 0.0;
    #pragma unroll
    for (int k4 = 0; k4 < 16; k4++){
      float4 xv = S->xs[k4*128 + t];
      float4 b = cbv[k4];
      float df, sq;
      df = xv.x - b.x; sq = df*df; dd += (double)sq;
      df = xv.y - b.y; sq = df*df; dd += (double)sq;
      df = xv.z - b.z; sq = df*df; dd += (double)sq;
      df = xv.w - b.w; sq = df*df; dd += (double)sq;
    }
    for (int off = 32; off > 0; off >>= 1) dd += __shfl_down(dd, off);
    if ((t & 63) == 0)
      atomicAdd(distacc, (unsigned long long)__double2ll_rn(dd * 4294967296.0));
  }
  __syncthreads();
}

// ---- Gather (4-deep load queue); caller guards bid < NBLK ----
template<int CURR, int NBLK>
__device__ void gather_ph(const float* __restrict__ x, const unsigned char* __restrict__ bidx8,
                          unsigned long long* __restrict__ sums, unsigned int* __restrict__ ndata,
                          int bid, int t, char* sm){
  SmemGather* S = (SmemGather*)sm;
  constexpr int CLOG = __builtin_ctz(CURR);
  constexpr int NCHUNK = NBLK / CURR;
  constexpr int PPC = NPTS / NCHUNK;
  constexpr int NPW = PPC / 4;
  const int lane = t & 63;
  const int w = t >> 6;
  const int c = bid & (CURR - 1);
  const int chunk = bid >> CLOG;
  const int pbase = chunk * PPC + w * NPW;

  long long acc = 0;
  unsigned int cnt = 0;
  int q0 = 0, q1 = 0, q2 = 0, q3 = 0, qn = 0;
  const uint32_t* bp = reinterpret_cast<const uint32_t*>(bidx8 + pbase);
  for (int i = 0; i < NPW; i += 256){
    const uint32_t b4 = bp[(i >> 2) + lane];
    #pragma unroll
    for (int s = 0; s < 4; s++){
      unsigned long long m = __ballot(((b4 >> (8*s)) & 255u) == (unsigned)c);
      cnt += (unsigned int)__popcll(m);
      while (m){
        const int bit = __builtin_ctzll(m);
        m &= m - 1ull;
        const int p = pbase + i + bit*4 + s;
        if      (qn == 0) q0 = p;
        else if (qn == 1) q1 = p;
        else if (qn == 2) q2 = p;
        else              q3 = p;
        qn++;
        if (qn == 4){
          const float v0 = x[(size_t)q0 * DIMS + lane];
          const float v1 = x[(size_t)q1 * DIMS + lane];
          const float v2 = x[(size_t)q2 * DIMS + lane];
          const float v3 = x[(size_t)q3 * DIMS + lane];
          acc += (long long)__double2int_rn((double)v0 * 1048576.0);
          acc += (long long)__double2int_rn((double)v1 * 1048576.0);
          acc += (long long)__double2int_rn((double)v2 * 1048576.0);
          acc += (long long)__double2int_rn((double)v3 * 1048576.0);
          qn = 0;
        }
      }
    }
  }
  if (qn > 0){
    const int i1 = (qn > 1) ? q1 : q0;
    const int i2 = (qn > 2) ? q2 : q0;
    const float v0 = x[(size_t)q0 * DIMS + lane];
    const float v1 = x[(size_t)i1 * DIMS + lane];
    const float v2 = x[(size_t)i2 * DIMS + lane];
    acc += (long long)__double2int_rn((double)v0 * 1048576.0);
    if (qn > 1) acc += (long long)__double2int_rn((double)v1 * 1048576.0);
    if (qn > 2) acc += (long long)__double2int_rn((double)v2 * 1048576.0);
  }
  S->sacc[w*64 + lane] = acc;
  if (lane == 0) S->scw[w] = cnt;
  __syncthreads();
  if (w == 0){
    long long tot = S->sacc[lane] + S->sacc[64+lane] + S->sacc[128+lane] + S->sacc[192+lane];
    if (tot) atomicAdd(&sums[c*DIMS + lane], (unsigned long long)(tot * 1048576ll));
    if (lane == 0){
      unsigned int ct = S->scw[0] + S->scw[1] + S->scw[2] + S->scw[3];
      if (ct) atomicAdd(&ndata[c], ct);
    }
  }
  __syncthreads();
}

// ---- control + (n==4) split/finalize (block 0 only) ----
__device__ void control_ph(float* __restrict__ cb, float* __restrict__ cnorm,
                           unsigned long long* __restrict__ sums,
                           unsigned int* __restrict__ ndata,
                           unsigned long long* __restrict__ distacc,
                           LbgState* __restrict__ st, int curr, int n_iter,
                           int next_split, int t, char* sm){
  SmemCtl* S = (SmemCtl*)sm;
  if (t == 0) S->sdone = st->done;
  __syncthreads();
  const unsigned int done0 = S->sdone;

  if (!done0){
    if (t == 0){
      double dd = (double)(long long)(*distacc) * (1.0/4294967296.0);
      float sf = (float)dd;
      float d_new = sf / 131072.0f;
      float change = fabsf(st->prev - d_new);
      int conv = (n_iter > 0) && (change / (d_new + 1e-16f) < 1e-5f);
      st->dist = d_new;
      if (!conv) st->prev = d_new;
      st->done = conv ? 1u : 0u;
      S->s_stop = conv;
      if (!conv){
        uint32_t a0, a1, b0, b1;
        tf2x32(st->k0, st->k1, 0u, 0u, a0, a1);
        tf2x32(st->k0, st->k1, 0u, 1u, b0, b1);
        st->k0 = a0; st->k1 = a1;
        S->sub0 = b0; S->sub1 = b1;
      }
    }
    __syncthreads();
    if (!S->s_stop){
      const uint32_t sub0 = S->sub0, sub1 = S->sub1;
      int v = (t < curr) ? (int)ndata[t] : -1;
      S->redv[t] = v; S->redi[t] = t;
      __syncthreads();
      for (int s = 128; s > 0; s >>= 1){
        if (t < s){
          if (S->redv[t+s] > S->redv[t] || (S->redv[t+s] == S->redv[t] && S->redi[t+s] < S->redi[t])){
            S->redv[t] = S->redv[t+s]; S->redi[t] = S->redi[t+s];
          }
        }
        __syncthreads();
      }
      if (t == 0) S->s_m = S->redi[0];
      __syncthreads();
      S->redv[t] = (t < curr && ndata[t] == 0u) ? 1 : 0;
      __syncthreads();
      for (int s = 128; s > 0; s >>= 1){
        if (t < s) S->redv[t] += S->redv[t+s];
        __syncthreads();
      }
      if (t == 0) S->s_cnt = S->redv[0];
      __syncthreads();
      const int m = S->s_m;
      const int cntE = S->s_cnt;

      if (t < 64){
        unsigned int nm_ = ndata[m]; if (nm_ < 1u) nm_ = 1u;
        double cd = (double)(long long)sums[m*DIMS + t] * (1.0/1099511627776.0) / (double)nm_;
        S->cm[t] = (float)cd;
      }
      __syncthreads();

      const int total = curr * DIMS;
      for (int e = t; e < total; e += 256){
        int c = e >> 6, d = e & 63;
        if (c == m) continue;
        float nv;
        unsigned int nd = ndata[c];
        if (nd >= 1u){
          double cd = (double)(long long)sums[e] * (1.0/1099511627776.0) / (double)nd;
          nv = (float)cd;
        } else {
          float rv = jax_normal_elem(sub0, sub1, (uint32_t)e) * 1e-5f;
          nv = S->cm[d] - rv;
        }
        cb[e] = nv;
      }
      if (t < 64){
        float add = 0.f;
        if (cntE > 0){
          float acc = 0.f;
          for (int c = 0; c < curr; c++){
            if (ndata[c] == 0u)
              acc += jax_normal_elem(sub0, sub1, (uint32_t)(c*DIMS + t)) * 1e-5f;
          }
          add = acc / fmaxf((float)cntE, 1.0f);
        }
        cb[m*DIMS + t] = S->cm[t] + add;
      }
      __syncthreads();

      for (int c = t; c < curr; c += 256){
        float s = 0.f;
        for (int d = 0; d < DIMS; d++){ float vv = cb[c*DIMS+d]; s += vv*vv; }
        cnorm[c] = s;
      }
      for (int e = t; e < total; e += 256) sums[e] = 0ull;
      for (int c = t; c < curr; c += 256) ndata[c] = 0u;
      if (t == 0) *distacc = 0ull;
    }
  }
  __syncthreads();
  if (n_iter == 4){
    if (curr < 256){
      do_split(cb, cnorm, sums, ndata, distacc, st, curr, next_split, t, sm);
    } else if (t == 0){
      cb[KCB*DIMS] = st->dist;               // finalize: out[16384] = distance
    }
  }
}

// ---- the persistent kernel (normal launch; own grid barrier) ----
__global__ __launch_bounds__(256, 2)
void lbg_kernel(const float* __restrict__ x, float* __restrict__ cb,
                unsigned long long* sums, unsigned long long* macc,
                unsigned long long* distacc, LbgState* st,
                unsigned int* ndata, float* cnorm, unsigned char* bidx8,
                GBar* gbar){
  __shared__ __align__(16) char smem[sizeof(SmemGemm)];
  const int t = threadIdx.x;
  const int bid = blockIdx.x;

  // mean (blocks 0..127)
  if (bid < 128) mean_phase(x, macc, bid, t, smem);
  grid_sync(gbar);

  // init + split0 (block 0)
  if (bid == 0){
    if (t < 64){
      long long mv = (long long)macc[t];
      double mean = (double)mv * (1.0/1099511627776.0) / 131072.0;
      cb[t] = (float)mean;
    }
    for (int e = t; e < KCB*DIMS; e += 256)
      if (e >= 64) cb[e] = 1e10f;
    if (t == 0){
      st->dist = __builtin_inff();
      st->prev = __builtin_inff();
      st->done = 0u;
    }
    __syncthreads();
    do_split(cb, cnorm, sums, ndata, distacc, st, 1, 0, t, smem);
  }
  grid_sync(gbar);

  for (int split = 0; split < 8; split++){
    for (int n = 0; n < 5; n++){
      const unsigned int done =
        __hip_atomic_load(&st->done, __ATOMIC_RELAXED, __HIP_MEMORY_SCOPE_AGENT);
      // ---- estep ----
      if (!done){
        switch (split){
          case 0: estep_small<2> (x, cb, cnorm, bidx8, distacc, bid, t); break;
          case 1: estep_small<4> (x, cb, cnorm, bidx8, distacc, bid, t); break;
          case 2: estep_small<8> (x, cb, cnorm, bidx8, distacc, bid, t); break;
          case 3: estep_small<16>(x, cb, cnorm, bidx8, distacc, bid, t); break;
          case 4: estep_small<32>(x, cb, cnorm, bidx8, distacc, bid, t); break;
          case 5: for (int r = 0; r < 2; r++) estep_gt<64> (x, cb, cnorm, bidx8, distacc, bid*2+r, t, smem); break;
          case 6: for (int r = 0; r < 2; r++) estep_gt<128>(x, cb, cnorm, bidx8, distacc, bid*2+r, t, smem); break;
          case 7: for (int r = 0; r < 2; r++) estep_gt<256>(x, cb, cnorm, bidx8, distacc, bid*2+r, t, smem); break;
        }
      }
      grid_sync(gbar);
      // ---- gather ----
      if (!done){
        switch (split){
          case 0: if (bid < 256) gather_ph<2,256>(x, bidx8, sums, ndata, bid, t, smem); break;
          case 1: gather_ph<4,512>  (x, bidx8, sums, ndata, bid, t, smem); break;
          case 2: gather_ph<8,512>  (x, bidx8, sums, ndata, bid, t, smem); break;
          case 3: gather_ph<16,512> (x, bidx8, sums, ndata, bid, t, smem); break;
          case 4: gather_ph<32,512> (x, bidx8, sums, ndata, bid, t, smem); break;
          case 5: gather_ph<64,512> (x, bidx8, sums, ndata, bid, t, smem); break;
          case 6: gather_ph<128,512>(x, bidx8, sums, ndata, bid, t, smem); break;
          case 7: gather_ph<256,512>(x, bidx8, sums, ndata, bid, t, smem); break;
        }
      }
      grid_sync(gbar);
      // ---- control (+split at n==4) ----
      if (bid == 0)
        control_ph(cb, cnorm, sums, ndata, distacc, st, 2 << split, n, split + 1, t, smem);
      grid_sync(gbar);
    }
  }
}

extern "C" void kernel_launch(void* const* d_in, const int* in_sizes, int n_in,
                              void* d_out, int out_size, void* d_ws, size_t ws_size,
                              hipStream_t stream){
  const float* x = (const float*)d_in[0];
  float* cb = (float*)d_out;
  char* ws = (char*)d_ws;
  unsigned long long* sums    = (unsigned long long*)(ws + 0);        // 131072 B
  unsigned long long* macc    = (unsigned long long*)(ws + 131072);   // 512 B
  unsigned long long* distacc = (unsigned long long*)(ws + 131584);   // 8 B
  LbgState* st                = (LbgState*)(ws + 131592);             // 24 B
  unsigned int* ndata         = (unsigned int*)(ws + 131616);         // 1024 B
  float* cnorm                = (float*)(ws + 132640);                // 1024 B
  unsigned char* bidx8        = (unsigned char*)(ws + 133664);        // 131072 B
  GBar* gbar                  = (GBar*)(ws + 264736);                 // 8 B

  hipMemsetAsync(d_ws, 0, 264752, stream);
  lbg_kernel<<<NBLKP, 256, 0, stream>>>(x, cb, sums, macc, distacc, st,
                                        ndata, cnorm, bidx8, gbar);
}

// Round 11
// 3775.508 us; speedup vs baseline: 4.3233x; 4.3233x over previous
//
#include <hip/hip_runtime.h>
#include <stdint.h>

// LBG vector quantization, bit-faithful port of the JAX ref.
// Round 11: revert persistent kernel (R10: in-kernel grid barriers cost an
// L2-coherency tax, 5x regression). Base = R8 (best, 3.33 ms) with:
// (a) estep for 128/256 = 4p x 8c / 64-cw-panel variant (79 vs 85 us, 3 blk/CU);
// (b) gather for CURR>=64: 8 clusters per block, bidx chunk staged in LDS
//     (global bidx traffic /8). Integer accumulation commutes and d2 chains
//     are unchanged => trajectory bit-identical (absmax 0.4985352).

#define NPTS 131072
#define DIMS 64
#define KCB  256

struct LbgState { float dist; float prev; unsigned int done; unsigned int k0, k1; unsigned int pad; };

__device__ __forceinline__ uint32_t rotl32(uint32_t v, int n){ return (v<<n)|(v>>(32-n)); }

// Threefry-2x32, 20 rounds (matches jax._src.prng.threefry2x32)
__device__ __forceinline__ void tf2x32(uint32_t k0, uint32_t k1, uint32_t x0, uint32_t x1,
                                       uint32_t& o0, uint32_t& o1){
  uint32_t ks2 = k0 ^ k1 ^ 0x1BD11BDAu;
  x0 += k0; x1 += k1;
  #define TFR(r) { x0 += x1; x1 = rotl32(x1, r); x1 ^= x0; }
  TFR(13) TFR(15) TFR(26) TFR(6)
  x0 += k1; x1 += ks2 + 1u;
  TFR(17) TFR(29) TFR(16) TFR(24)
  x0 += ks2; x1 += k0 + 2u;
  TFR(13) TFR(15) TFR(26) TFR(6)
  x0 += k0; x1 += k1 + 3u;
  TFR(17) TFR(29) TFR(16) TFR(24)
  x0 += k1; x1 += ks2 + 4u;
  TFR(13) TFR(15) TFR(26) TFR(6)
  x0 += ks2; x1 += k0 + 5u;
  #undef TFR
  o0 = x0; o1 = x1;
}

// XLA ErfInv (f32, Giles polynomial)
__device__ __forceinline__ float xla_erfinv_f32(float x){
  float w = -log1pf(-x*x);
  float p;
  if (w < 5.0f){
    w = w - 2.5f;
    p = 2.81022636e-08f;
    p = fmaf(p, w, 3.43273939e-07f);
    p = fmaf(p, w, -3.5233877e-06f);
    p = fmaf(p, w, -4.39150654e-06f);
    p = fmaf(p, w, 0.00021858087f);
    p = fmaf(p, w, -0.00125372503f);
    p = fmaf(p, w, -0.00417768164f);
    p = fmaf(p, w, 0.246640727f);
    p = fmaf(p, w, 1.50140941f);
  } else {
    w = sqrtf(w) - 3.0f;
    p = -0.000200214257f;
    p = fmaf(p, w, 0.000100950558f);
    p = fmaf(p, w, 0.00134934322f);
    p = fmaf(p, w, -0.00367342844f);
    p = fmaf(p, w, 0.00573950773f);
    p = fmaf(p, w, -0.0076224613f);
    p = fmaf(p, w, 0.00943887047f);
    p = fmaf(p, w, 1.00167406f);
    p = fmaf(p, w, 2.83297682f);
  }
  return p * x;
}

__device__ __forceinline__ float jax_normal_elem(uint32_t k0, uint32_t k1, uint32_t j){
  uint32_t o0, o1; tf2x32(k0, k1, 0u, j, o0, o1);
  uint32_t bits = o0 ^ o1;
  uint32_t fb = (bits >> 9) | 0x3f800000u;
  float f = __uint_as_float(fb) - 1.0f;
  const float lo = -0.99999994f;
  float u = f * 2.0f + lo;
  u = fmaxf(lo, u);
  return 1.41421356f * xla_erfinv_f32(u);
}

// --- split phase (used by mean last-block for split0 and control at n==4) ---
__device__ void do_split(float* __restrict__ cb, float* __restrict__ cnorm,
                         unsigned long long* __restrict__ sums,
                         unsigned int* __restrict__ ndata,
                         unsigned long long* __restrict__ distacc,
                         LbgState* __restrict__ st, int curr, int split, int t){
  __shared__ uint32_t kr0s, kr1s;
  if (t == 0){
    uint32_t ks0, ks1, a0, a1, b0, b1;
    tf2x32(0u, 42u, 0u, (uint32_t)split, ks0, ks1);
    tf2x32(ks0, ks1, 0u, 0u, a0, a1);
    tf2x32(ks0, ks1, 0u, 1u, b0, b1);
    kr0s = a0; kr1s = a1;
    st->k0 = b0; st->k1 = b1;
    st->prev = st->dist;
    st->done = 0u;
  }
  __syncthreads();
  const int n = curr * DIMS;
  for (int e = t; e < n; e += 256){
    int c = e >> 6, d = e & 63;
    float rv = jax_normal_elem(kr0s, kr1s, (uint32_t)e) * 1e-5f;
    float old = cb[c*DIMS + d];
    cb[(curr + c)*DIMS + d] = old - rv;
    cb[c*DIMS + d]          = old + rv;
  }
  __syncthreads();
  const int c2 = curr * 2;
  for (int c = t; c < c2; c += 256){
    float s = 0.f;
    for (int d = 0; d < DIMS; d++){ float vv = cb[c*DIMS+d]; s += vv*vv; }
    cnorm[c] = s;
  }
  for (int e = t; e < c2*DIMS; e += 256) sums[e] = 0ull;
  for (int c = t; c < c2; c += 256) ndata[c] = 0u;
  if (t == 0) *distacc = 0ull;
}

// --- mean of x (LDS-tiled) + last block does init + split0 ---
__global__ void mean_kernel(const float* __restrict__ x, unsigned long long* __restrict__ macc,
                            float* __restrict__ cb, float* __restrict__ cnorm,
                            unsigned long long* __restrict__ sums,
                            unsigned int* __restrict__ ndata,
                            unsigned long long* __restrict__ distacc,
                            LbgState* __restrict__ st, unsigned int* __restrict__ mcnt){
  __shared__ double part[256];
  __shared__ float stage[16*64];
  __shared__ int islast;
  const int t = threadIdx.x;
  const int d = t & 63;
  const int w = t >> 6;
  const size_t base = (size_t)blockIdx.x * 1024;
  const int lrow = t >> 4;
  const int lcol = (t & 15) * 4;

  const float4* xg = reinterpret_cast<const float4*>(x);
  float4 nxt = xg[((base + lrow) * DIMS + lcol) >> 2];
  double s = 0.0;
  for (int tt = 0; tt < 64; tt++){
    float4 cur = nxt;
    if (tt < 63)
      nxt = xg[((base + (tt+1)*16 + lrow) * DIMS + lcol) >> 2];
    __syncthreads();
    *reinterpret_cast<float4*>(&stage[lrow*DIMS + lcol]) = cur;
    __syncthreads();
    s += (double)stage[(w    )*DIMS + d];
    s += (double)stage[(w + 4)*DIMS + d];
    s += (double)stage[(w + 8)*DIMS + d];
    s += (double)stage[(w +12)*DIMS + d];
  }
  part[t] = s;
  __syncthreads();
  if (t < 64){
    double tot = part[t] + part[64+t] + part[128+t] + part[192+t];
    atomicAdd(&macc[t], (unsigned long long)__double2ll_rn(tot * 1099511627776.0));
  }
  __threadfence();
  __syncthreads();
  if (t == 0) islast = (atomicAdd(mcnt, 1u) == (unsigned)(gridDim.x - 1));
  __syncthreads();
  if (!islast) return;

  if (t < 64){
    long long mv = (long long)atomicAdd(&macc[t], 0ull);
    double mean = (double)mv * (1.0/1099511627776.0) / 131072.0;
    cb[t] = (float)mean;
  }
  for (int e = t; e < KCB*DIMS; e += 256)
    if (e >= 64) cb[e] = 1e10f;
  if (t == 0){
    st->dist = __builtin_inff();
    st->prev = __builtin_inff();
    st->done = 0u;
    atomicExch(mcnt, 0u);
  }
  __syncthreads();
  do_split(cb, cnorm, sums, ndata, distacc, st, 1, 0, t);
}

// --- E-step for small CURR (<=32): one thread per point ---
template<int CURR>
__global__ __launch_bounds__(256, 4)
void estep_kernel(const float* __restrict__ x, const float* __restrict__ cb,
                  const float* __restrict__ cnorm, unsigned char* __restrict__ bidx8,
                  unsigned long long* __restrict__ distacc, const LbgState* __restrict__ st){
  if (st->done) return;
  const int t = threadIdx.x;
  const int lane = t & 63;
  const int p = blockIdx.x * 256 + t;

  float xv[DIMS];
  const float4* xp = reinterpret_cast<const float4*>(x + (size_t)p * DIMS);
  #pragma unroll
  for (int i = 0; i < 16; i++){
    float4 v = xp[i];
    xv[4*i+0] = v.x; xv[4*i+1] = v.y; xv[4*i+2] = v.z; xv[4*i+3] = v.w;
  }
  float xx = 0.f;
  #pragma unroll
  for (int d = 0; d < DIMS; d++) xx += xv[d] * xv[d];

  constexpr int NJ = (CURR < 4) ? CURR : 4;
  float best = __builtin_inff();
  int bi = 0;
  for (int j0 = 0; j0 < CURR; j0 += NJ){
    const float* crow = cb + (size_t)j0 * DIMS;
    float acc[NJ];
    #pragma unroll
    for (int k = 0; k < NJ; k++) acc[k] = 0.f;
    #pragma unroll
    for (int d = 0; d < DIMS; d++){
      #pragma unroll
      for (int k = 0; k < NJ; k++)
        acc[k] = fmaf(xv[d], crow[k*DIMS + d], acc[k]);
    }
    #pragma unroll
    for (int k = 0; k < NJ; k++){
      float d2 = (xx - 2.0f*acc[k]) + cnorm[j0 + k];
      if (d2 < best){ best = d2; bi = j0 + k; }
    }
  }
  bidx8[p] = (unsigned char)bi;

  double dd = 0.0;
  const float4* cbv = reinterpret_cast<const float4*>(cb + (size_t)bi * DIMS);
  #pragma unroll
  for (int i = 0; i < 16; i++){
    float4 b = cbv[i];
    float df, sq;
    df = xv[4*i+0] - b.x; sq = df*df; dd += (double)sq;
    df = xv[4*i+1] - b.y; sq = df*df; dd += (double)sq;
    df = xv[4*i+2] - b.z; sq = df*df; dd += (double)sq;
    df = xv[4*i+3] - b.w; sq = df*df; dd += (double)sq;
  }
  for (int off = 32; off > 0; off >>= 1) dd += __shfl_down(dd, off);
  if (lane == 0)
    atomicAdd(distacc, (unsigned long long)__double2ll_rn(dd * 4294967296.0));
}

// --- E-step CURR in {64,128,256}: 4p x 8c tile, 64-cw panels (50 KB LDS, 3/CU) ---
template<int CURR>
__global__ __launch_bounds__(256, 3)
void estep_gemm(const float* __restrict__ x, const float* __restrict__ cb,
                const float* __restrict__ cnorm, unsigned char* __restrict__ bidx8,
                unsigned long long* __restrict__ distacc, const LbgState* __restrict__ st){
  if (st->done) return;
  constexpr int NPANEL = CURR / 64;
  __shared__ float4 xs[16*128];
  __shared__ float4 cbs[64*16];
  __shared__ float sxx[128];
  __shared__ unsigned char sbidx[128];
  const int t = threadIdx.x;
  const int pbase = blockIdx.x * 128;

  {
    const int p = t & 127, h = t >> 7;
    const float4* xg = reinterpret_cast<const float4*>(x) + (size_t)(pbase + p) * 16 + h * 8;
    #pragma unroll
    for (int j = 0; j < 8; j++)
      xs[(h*8 + j)*128 + p] = xg[j];
  }
  __syncthreads();
  if (t < 128){
    float xx = 0.f;
    #pragma unroll
    for (int k4 = 0; k4 < 16; k4++){
      float4 v = xs[k4*128 + t];
      xx = fmaf(v.x, v.x, xx); xx = fmaf(v.y, v.y, xx);
      xx = fmaf(v.z, v.z, xx); xx = fmaf(v.w, v.w, xx);
    }
    sxx[t] = xx;
  }
  __syncthreads();

  const int cg = t & 7;
  const int pg = t >> 3;
  float best[4] = {__builtin_inff(), __builtin_inff(), __builtin_inff(), __builtin_inff()};
  int bidx[4] = {0,0,0,0};
  float xxv[4];
  #pragma unroll
  for (int j = 0; j < 4; j++) xxv[j] = sxx[pg + 32*j];

  const float4* cbg = reinterpret_cast<const float4*>(cb);
  for (int panel = 0; panel < NPANEL; panel++){
    __syncthreads();
    for (int idx = t; idx < 1024; idx += 256){
      const int cl = idx >> 4, kk = idx & 15;
      cbs[cl*16 + (kk ^ (cl >> 3))] = cbg[(size_t)(panel*64 + cl)*16 + kk];
    }
    __syncthreads();

    const int c0 = panel*64 + cg*8;
    float acc[4][8];
    #pragma unroll
    for (int j = 0; j < 4; j++)
      #pragma unroll
      for (int cj = 0; cj < 8; cj++) acc[j][cj] = 0.f;

    for (int k4 = 0; k4 < 16; k4++){
      float4 xf[4];
      #pragma unroll
      for (int j = 0; j < 4; j++) xf[j] = xs[k4*128 + pg + 32*j];
      #pragma unroll
      for (int cj = 0; cj < 8; cj++){
        float4 cf = cbs[(cg*8 + cj)*16 + (k4 ^ cg)];
        #pragma unroll
        for (int j = 0; j < 4; j++){
          acc[j][cj] = fmaf(xf[j].x, cf.x, acc[j][cj]);
          acc[j][cj] = fmaf(xf[j].y, cf.y, acc[j][cj]);
          acc[j][cj] = fmaf(xf[j].z, cf.z, acc[j][cj]);
          acc[j][cj] = fmaf(xf[j].w, cf.w, acc[j][cj]);
        }
      }
    }
    #pragma unroll
    for (int cj = 0; cj < 8; cj++){
      float cn = cnorm[c0 + cj];
      #pragma unroll
      for (int j = 0; j < 4; j++){
        float d2 = (xxv[j] - 2.0f*acc[j][cj]) + cn;
        if (d2 < best[j]){ best[j] = d2; bidx[j] = c0 + cj; }
      }
    }
  }
  #pragma unroll
  for (int m = 1; m < 8; m <<= 1){
    #pragma unroll
    for (int j = 0; j < 4; j++){
      float ob = __shfl_xor(best[j], m, 64);
      int   oc = __shfl_xor(bidx[j], m, 64);
      if (ob < best[j] || (ob == best[j] && oc < bidx[j])){ best[j] = ob; bidx[j] = oc; }
    }
  }
  if (cg == 0){
    #pragma unroll
    for (int j = 0; j < 4; j++) sbidx[pg + 32*j] = (unsigned char)bidx[j];
  }
  __syncthreads();
  if (t < 128){
    const int bi = (int)sbidx[t];
    bidx8[pbase + t] = (unsigned char)bi;
    const float4* cbv = cbg + (size_t)bi * 16;
    double dd = 0.0;
    #pragma unroll
    for (int k4 = 0; k4 < 16; k4++){
      float4 xv = xs[k4*128 + t];
      float4 b = cbv[k4];
      float df, sq;
      df = xv.x - b.x; sq = df*df; dd += (double)sq;
      df = xv.y - b.y; sq = df*df; dd += (double)sq;
      df = xv.z - b.z; sq = df*df; dd += (double)sq;
      df = xv.w - b.w; sq = df*df; dd += (double)sq;
    }
    for (int off = 32; off > 0; off >>= 1) dd += __shfl_down(dd, off);
    if ((t & 63) == 0)
      atomicAdd(distacc, (unsigned long long)__double2ll_rn(dd * 4294967296.0));
  }
}

// --- Gather small CURR (<=32): R8 version (dword scan + 4-deep load queue) ---
template<int CURR, int NBLK>
__global__ __launch_bounds__(256)
void gather_kernel(const float* __restrict__ x, const unsigned char* __restrict__ bidx8,
                   unsigned long long* __restrict__ sums, unsigned int* __restrict__ ndata,
                   const LbgState* __restrict__ st){
  if (st->done) return;
  constexpr int CLOG = __builtin_ctz(CURR);
  constexpr int NCHUNK = NBLK / CURR;
  constexpr int PPC = NPTS / NCHUNK;
  constexpr int NPW = PPC / 4;
  __shared__ long long sacc[4*64];
  __shared__ unsigned int scw[4];
  const int t = threadIdx.x;
  const int lane = t & 63;
  const int w = t >> 6;
  const int c = blockIdx.x & (CURR - 1);
  const int chunk = blockIdx.x >> CLOG;
  const int pbase = chunk * PPC + w * NPW;

  long long acc = 0;
  unsigned int cnt = 0;
  int q0 = 0, q1 = 0, q2 = 0, q3 = 0, qn = 0;
  const uint32_t* bp = reinterpret_cast<const uint32_t*>(bidx8 + pbase);
  for (int i = 0; i < NPW; i += 256){
    const uint32_t b4 = bp[(i >> 2) + lane];
    #pragma unroll
    for (int s = 0; s < 4; s++){
      unsigned long long m = __ballot(((b4 >> (8*s)) & 255u) == (unsigned)c);
      cnt += (unsigned int)__popcll(m);
      while (m){
        const int bit = __builtin_ctzll(m);
        m &= m - 1ull;
        const int p = pbase + i + bit*4 + s;
        if      (qn == 0) q0 = p;
        else if (qn == 1) q1 = p;
        else if (qn == 2) q2 = p;
        else              q3 = p;
        qn++;
        if (qn == 4){
          const float v0 = x[(size_t)q0 * DIMS + lane];
          const float v1 = x[(size_t)q1 * DIMS + lane];
          const float v2 = x[(size_t)q2 * DIMS + lane];
          const float v3 = x[(size_t)q3 * DIMS + lane];
          acc += (long long)__double2int_rn((double)v0 * 1048576.0);
          acc += (long long)__double2int_rn((double)v1 * 1048576.0);
          acc += (long long)__double2int_rn((double)v2 * 1048576.0);
          acc += (long long)__double2int_rn((double)v3 * 1048576.0);
          qn = 0;
        }
      }
    }
  }
  if (qn > 0){
    const int i1 = (qn > 1) ? q1 : q0;
    const int i2 = (qn > 2) ? q2 : q0;
    const float v0 = x[(size_t)q0 * DIMS + lane];
    const float v1 = x[(size_t)i1 * DIMS + lane];
    const float v2 = x[(size_t)i2 * DIMS + lane];
    acc += (long long)__double2int_rn((double)v0 * 1048576.0);
    if (qn > 1) acc += (long long)__double2int_rn((double)v1 * 1048576.0);
    if (qn > 2) acc += (long long)__double2int_rn((double)v2 * 1048576.0);
  }
  sacc[w*64 + lane] = acc;
  if (lane == 0) scw[w] = cnt;
  __syncthreads();
  if (w == 0){
    long long tot = sacc[lane] + sacc[64+lane] + sacc[128+lane] + sacc[192+lane];
    if (tot) atomicAdd(&sums[c*DIMS + lane], (unsigned long long)(tot * 1048576ll));
    if (lane == 0){
      unsigned int ct = scw[0] + scw[1] + scw[2] + scw[3];
      if (ct) atomicAdd(&ndata[c], ct);
    }
  }
}

// --- Gather CURR>=64: 8 clusters per block, bidx chunk staged in LDS. ---
// 256 blocks = (CURR/8 cluster-groups) x (2048/CURR chunks). Global bidx
// traffic drops 8x; each x row still loaded exactly once (by its cluster's
// block). Same quantization + commuting int adds => bit-identical sums.
template<int CURR>
__global__ __launch_bounds__(256)
void gather8_kernel(const float* __restrict__ x, const unsigned char* __restrict__ bidx8,
                    unsigned long long* __restrict__ sums, unsigned int* __restrict__ ndata,
                    const LbgState* __restrict__ st){
  if (st->done) return;
  constexpr int G = 8;
  constexpr int CG = CURR / G;            // cluster-groups (8..32)
  constexpr int NCHUNK = 256 / CG;        // 32..8 chunks
  constexpr int PPC = NPTS / NCHUNK;      // 4096..16384 points per chunk
  constexpr int NPW = PPC / 4;            // per-wave quarter (>=1024, mult of 256)
  __shared__ long long sacc[4*64];
  __shared__ unsigned int scw[4];
  __shared__ uint32_t bstage[PPC/4];      // <= 16 KB
  const int t = threadIdx.x;
  const int lane = t & 63;
  const int w = t >> 6;
  const int cbase = (blockIdx.x % CG) * G;
  const int chunk = blockIdx.x / CG;

  const uint32_t* bg = reinterpret_cast<const uint32_t*>(bidx8) + chunk * (PPC/4);
  for (int idx = t; idx < PPC/4; idx += 256) bstage[idx] = bg[idx];
  __syncthreads();

  const int pbase = chunk * PPC + w * NPW;
  const int dwbase = (w * NPW) >> 2;
  for (int g = 0; g < G; g++){
    const int c = cbase + g;
    long long acc = 0;
    unsigned int cnt = 0;
    int q0 = 0, q1 = 0, q2 = 0, q3 = 0, qn = 0;
    for (int i = 0; i < NPW; i += 256){
      const uint32_t b4 = bstage[dwbase + (i >> 2) + lane];
      #pragma unroll
      for (int s = 0; s < 4; s++){
        unsigned long long m = __ballot(((b4 >> (8*s)) & 255u) == (unsigned)c);
        cnt += (unsigned int)__popcll(m);
        while (m){
          const int bit = __builtin_ctzll(m);
          m &= m - 1ull;
          const int p = pbase + i + bit*4 + s;
          if      (qn == 0) q0 = p;
          else if (qn == 1) q1 = p;
          else if (qn == 2) q2 = p;
          else              q3 = p;
          qn++;
          if (qn == 4){
            const float v0 = x[(size_t)q0 * DIMS + lane];
            const float v1 = x[(size_t)q1 * DIMS + lane];
            const float v2 = x[(size_t)q2 * DIMS + lane];
            const float v3 = x[(size_t)q3 * DIMS + lane];
            acc += (long long)__double2int_rn((double)v0 * 1048576.0);
            acc += (long long)__double2int_rn((double)v1 * 1048576.0);
            acc += (long long)__double2int_rn((double)v2 * 1048576.0);
            acc += (long long)__double2int_rn((double)v3 * 1048576.0);
            qn = 0;
          }
        }
      }
    }
    if (qn > 0){
      const int i1 = (qn > 1) ? q1 : q0;
      const int i2 = (qn > 2) ? q2 : q0;
      const float v0 = x[(size_t)q0 * DIMS + lane];
      const float v1 = x[(size_t)i1 * DIMS + lane];
      const float v2 = x[(size_t)i2 * DIMS + lane];
      acc += (long long)__double2int_rn((double)v0 * 1048576.0);
      if (qn > 1) acc += (long long)__double2int_rn((double)v1 * 1048576.0);
      if (qn > 2) acc += (long long)__double2int_rn((double)v2 * 1048576.0);
    }
    sacc[w*64 + lane] = acc;
    if (lane == 0) scw[w] = cnt;
    __syncthreads();
    if (w == 0){
      long long tot = sacc[lane] + sacc[64+lane] + sacc[128+lane] + sacc[192+lane];
      if (tot) atomicAdd(&sums[c*DIMS + lane], (unsigned long long)(tot * 1048576ll));
      if (lane == 0){
        unsigned int ct = scw[0] + scw[1] + scw[2] + scw[3];
        if (ct) atomicAdd(&ndata[c], ct);
      }
    }
    __syncthreads();
  }
}

// --- convergence + M-step finalize + (n==4) split/finalize (one block) ---
__global__ void control_kernel(float* __restrict__ cb, float* __restrict__ cnorm,
                               unsigned long long* __restrict__ sums,
                               unsigned int* __restrict__ ndata,
                               unsigned long long* __restrict__ distacc,
                               LbgState* __restrict__ st, int curr, int n_iter,
                               int next_split){
  __shared__ int s_stop;
  __shared__ unsigned int sdone;
  __shared__ uint32_t sub0, sub1;
  __shared__ float cm[64];
  __shared__ int redv[256];
  __shared__ int redi[256];
  __shared__ int s_m, s_cnt;
  const int t = threadIdx.x;
  if (t == 0) sdone = st->done;
  __syncthreads();
  const unsigned int done0 = sdone;

  if (!done0){
    if (t == 0){
      double dd = (double)(long long)(*distacc) * (1.0/4294967296.0);
      float sf = (float)dd;
      float d_new = sf / 131072.0f;
      float change = fabsf(st->prev - d_new);
      int conv = (n_iter > 0) && (change / (d_new + 1e-16f) < 1e-5f);
      st->dist = d_new;
      if (!conv) st->prev = d_new;
      st->done = conv ? 1u : 0u;
      s_stop = conv;
      if (!conv){
        uint32_t a0, a1, b0, b1;
        tf2x32(st->k0, st->k1, 0u, 0u, a0, a1);
        tf2x32(st->k0, st->k1, 0u, 1u, b0, b1);
        st->k0 = a0; st->k1 = a1;
        sub0 = b0; sub1 = b1;
      }
    }
    __syncthreads();
    if (!s_stop){
      int v = (t < curr) ? (int)ndata[t] : -1;
      redv[t] = v; redi[t] = t;
      __syncthreads();
      for (int s = 128; s > 0; s >>= 1){
        if (t < s){
          if (redv[t+s] > redv[t] || (redv[t+s] == redv[t] && redi[t+s] < redi[t])){
            redv[t] = redv[t+s]; redi[t] = redi[t+s];
          }
        }
        __syncthreads();
      }
      if (t == 0) s_m = redi[0];
      __syncthreads();
      redv[t] = (t < curr && ndata[t] == 0u) ? 1 : 0;
      __syncthreads();
      for (int s = 128; s > 0; s >>= 1){
        if (t < s) redv[t] += redv[t+s];
        __syncthreads();
      }
      if (t == 0) s_cnt = redv[0];
      __syncthreads();
      const int m = s_m;
      const int cntE = s_cnt;

      if (t < 64){
        unsigned int nm_ = ndata[m]; if (nm_ < 1u) nm_ = 1u;
        double cd = (double)(long long)sums[m*DIMS + t] * (1.0/1099511627776.0) / (double)nm_;
        cm[t] = (float)cd;
      }
      __syncthreads();

      const int total = curr * DIMS;
      for (int e = t; e < total; e += 256){
        int c = e >> 6, d = e & 63;
        if (c == m) continue;
        float nv;
        unsigned int nd = ndata[c];
        if (nd >= 1u){
          double cd = (double)(long long)sums[e] * (1.0/1099511627776.0) / (double)nd;
          nv = (float)cd;
        } else {
          float rv = jax_normal_elem(sub0, sub1, (uint32_t)e) * 1e-5f;
          nv = cm[d] - rv;
        }
        cb[e] = nv;
      }
      if (t < 64){
        float add = 0.f;
        if (cntE > 0){
          float acc = 0.f;
          for (int c = 0; c < curr; c++){
            if (ndata[c] == 0u)
              acc += jax_normal_elem(sub0, sub1, (uint32_t)(c*DIMS + t)) * 1e-5f;
          }
          add = acc / fmaxf((float)cntE, 1.0f);
        }
        cb[m*DIMS + t] = cm[t] + add;
      }
      __syncthreads();

      for (int c = t; c < curr; c += 256){
        float s = 0.f;
        for (int d = 0; d < DIMS; d++){ float vv = cb[c*DIMS+d]; s += vv*vv; }
        cnorm[c] = s;
      }
      for (int e = t; e < total; e += 256) sums[e] = 0ull;
      for (int c = t; c < curr; c += 256) ndata[c] = 0u;
      if (t == 0) *distacc = 0ull;
    }
  }
  __syncthreads();
  if (n_iter == 4){
    if (curr < 256){
      do_split(cb, cnorm, sums, ndata, distacc, st, curr, next_split, t);
    } else if (t == 0){
      cb[KCB*DIMS] = st->dist;               // finalize: out[16384] = distance
    }
  }
}

extern "C" void kernel_launch(void* const* d_in, const int* in_sizes, int n_in,
                              void* d_out, int out_size, void* d_ws, size_t ws_size,
                              hipStream_t stream){
  const float* x = (const float*)d_in[0];
  float* cb = (float*)d_out;
  char* ws = (char*)d_ws;
  unsigned long long* sums    = (unsigned long long*)(ws + 0);        // 131072 B
  unsigned long long* macc    = (unsigned long long*)(ws + 131072);   // 512 B
  unsigned long long* distacc = (unsigned long long*)(ws + 131584);   // 8 B
  LbgState* st                = (LbgState*)(ws + 131592);             // 24 B
  unsigned int* ndata         = (unsigned int*)(ws + 131616);         // 1024 B
  float* cnorm                = (float*)(ws + 132640);                // 1024 B
  unsigned char* bidx8        = (unsigned char*)(ws + 133664);        // 131072 B
  unsigned int* mcnt          = (unsigned int*)(ws + 264736);         // 4 B

  hipMemsetAsync(d_ws, 0, 264744, stream);
  mean_kernel<<<128, 256, 0, stream>>>(x, macc, cb, cnorm, sums, ndata, distacc, st, mcnt);

  for (int split = 0; split < 8; split++){
    const int curr = 2 << split;
    for (int n = 0; n < 5; n++){
      switch (curr){
        case 2:   estep_kernel<2>  <<<512,256,0,stream>>>(x,cb,cnorm,bidx8,distacc,st);
                  gather_kernel<2,256>   <<<256, 256,0,stream>>>(x,bidx8,sums,ndata,st); break;
        case 4:   estep_kernel<4>  <<<512,256,0,stream>>>(x,cb,cnorm,bidx8,distacc,st);
                  gather_kernel<4,512>   <<<512, 256,0,stream>>>(x,bidx8,sums,ndata,st); break;
        case 8:   estep_kernel<8>  <<<512,256,0,stream>>>(x,cb,cnorm,bidx8,distacc,st);
                  gather_kernel<8,512>   <<<512, 256,0,stream>>>(x,bidx8,sums,ndata,st); break;
        case 16:  estep_kernel<16> <<<512,256,0,stream>>>(x,cb,cnorm,bidx8,distacc,st);
                  gather_kernel<16,512>  <<<512, 256,0,stream>>>(x,bidx8,sums,ndata,st); break;
        case 32:  estep_kernel<32> <<<512,256,0,stream>>>(x,cb,cnorm,bidx8,distacc,st);
                  gather_kernel<32,512>  <<<512, 256,0,stream>>>(x,bidx8,sums,ndata,st); break;
        case 64:  estep_gemm<64>  <<<1024,256,0,stream>>>(x,cb,cnorm,bidx8,distacc,st);
                  gather8_kernel<64>     <<<256, 256,0,stream>>>(x,bidx8,sums,ndata,st); break;
        case 128: estep_gemm<128> <<<1024,256,0,stream>>>(x,cb,cnorm,bidx8,distacc,st);
                  gather8_kernel<128>    <<<256, 256,0,stream>>>(x,bidx8,sums,ndata,st); break;
        case 256: estep_gemm<256> <<<1024,256,0,stream>>>(x,cb,cnorm,bidx8,distacc,st);
                  gather8_kernel<256>    <<<256, 256,0,stream>>>(x,bidx8,sums,ndata,st); break;
      }
      control_kernel<<<1, 256, 0, stream>>>(cb, cnorm, sums, ndata, distacc, st, curr, n, split+1);
    }
  }
}

// Round 12
// 3610.734 us; speedup vs baseline: 4.5206x; 1.0456x over previous
//
#include <hip/hip_runtime.h>
#include <stdint.h>

// LBG vector quantization, bit-faithful port of the JAX ref.
// Round 12: base = R8 (best structure: its gather grids + control). Changes:
// (a) estep for 64/128/256 = 4p x 8c / 64-cw-panel (R11-verified, 81 vs 85 us)
//     with REGISTER DOUBLE-BUFFERED k4 loop (prefetch next k4's xf/cf before
//     current FMAs; VGPR 68 -> ~130, hides ds_read latency);
// (b) gather reverted to R8's (2048 blocks at CURR=256 — TLP for latency-bound
//     row loads; R11's 256-block version starved it).
// FMA chain order unchanged => bit-identical trajectory (absmax 0.4985352).

#define NPTS 131072
#define DIMS 64
#define KCB  256

struct LbgState { float dist; float prev; unsigned int done; unsigned int k0, k1; unsigned int pad; };

__device__ __forceinline__ uint32_t rotl32(uint32_t v, int n){ return (v<<n)|(v>>(32-n)); }

// Threefry-2x32, 20 rounds (matches jax._src.prng.threefry2x32)
__device__ __forceinline__ void tf2x32(uint32_t k0, uint32_t k1, uint32_t x0, uint32_t x1,
                                       uint32_t& o0, uint32_t& o1){
  uint32_t ks2 = k0 ^ k1 ^ 0x1BD11BDAu;
  x0 += k0; x1 += k1;
  #define TFR(r) { x0 += x1; x1 = rotl32(x1, r); x1 ^= x0; }
  TFR(13) TFR(15) TFR(26) TFR(6)
  x0 += k1; x1 += ks2 + 1u;
  TFR(17) TFR(29) TFR(16) TFR(24)
  x0 += ks2; x1 += k0 + 2u;
  TFR(13) TFR(15) TFR(26) TFR(6)
  x0 += k0; x1 += k1 + 3u;
  TFR(17) TFR(29) TFR(16) TFR(24)
  x0 += k1; x1 += ks2 + 4u;
  TFR(13) TFR(15) TFR(26) TFR(6)
  x0 += ks2; x1 += k0 + 5u;
  #undef TFR
  o0 = x0; o1 = x1;
}

// XLA ErfInv (f32, Giles polynomial)
__device__ __forceinline__ float xla_erfinv_f32(float x){
  float w = -log1pf(-x*x);
  float p;
  if (w < 5.0f){
    w = w - 2.5f;
    p = 2.81022636e-08f;
    p = fmaf(p, w, 3.43273939e-07f);
    p = fmaf(p, w, -3.5233877e-06f);
    p = fmaf(p, w, -4.39150654e-06f);
    p = fmaf(p, w, 0.00021858087f);
    p = fmaf(p, w, -0.00125372503f);
    p = fmaf(p, w, -0.00417768164f);
    p = fmaf(p, w, 0.246640727f);
    p = fmaf(p, w, 1.50140941f);
  } else {
    w = sqrtf(w) - 3.0f;
    p = -0.000200214257f;
    p = fmaf(p, w, 0.000100950558f);
    p = fmaf(p, w, 0.00134934322f);
    p = fmaf(p, w, -0.00367342844f);
    p = fmaf(p, w, 0.00573950773f);
    p = fmaf(p, w, -0.0076224613f);
    p = fmaf(p, w, 0.00943887047f);
    p = fmaf(p, w, 1.00167406f);
    p = fmaf(p, w, 2.83297682f);
  }
  return p * x;
}

__device__ __forceinline__ float jax_normal_elem(uint32_t k0, uint32_t k1, uint32_t j){
  uint32_t o0, o1; tf2x32(k0, k1, 0u, j, o0, o1);
  uint32_t bits = o0 ^ o1;
  uint32_t fb = (bits >> 9) | 0x3f800000u;
  float f = __uint_as_float(fb) - 1.0f;
  const float lo = -0.99999994f;
  float u = f * 2.0f + lo;
  u = fmaxf(lo, u);
  return 1.41421356f * xla_erfinv_f32(u);
}

// --- split phase (used by mean last-block for split0 and control at n==4) ---
__device__ void do_split(float* __restrict__ cb, float* __restrict__ cnorm,
                         unsigned long long* __restrict__ sums,
                         unsigned int* __restrict__ ndata,
                         unsigned long long* __restrict__ distacc,
                         LbgState* __restrict__ st, int curr, int split, int t){
  __shared__ uint32_t kr0s, kr1s;
  if (t == 0){
    uint32_t ks0, ks1, a0, a1, b0, b1;
    tf2x32(0u, 42u, 0u, (uint32_t)split, ks0, ks1);
    tf2x32(ks0, ks1, 0u, 0u, a0, a1);
    tf2x32(ks0, ks1, 0u, 1u, b0, b1);
    kr0s = a0; kr1s = a1;
    st->k0 = b0; st->k1 = b1;
    st->prev = st->dist;
    st->done = 0u;
  }
  __syncthreads();
  const int n = curr * DIMS;
  for (int e = t; e < n; e += 256){
    int c = e >> 6, d = e & 63;
    float rv = jax_normal_elem(kr0s, kr1s, (uint32_t)e) * 1e-5f;
    float old = cb[c*DIMS + d];
    cb[(curr + c)*DIMS + d] = old - rv;
    cb[c*DIMS + d]          = old + rv;
  }
  __syncthreads();
  const int c2 = curr * 2;
  for (int c = t; c < c2; c += 256){
    float s = 0.f;
    for (int d = 0; d < DIMS; d++){ float vv = cb[c*DIMS+d]; s += vv*vv; }
    cnorm[c] = s;
  }
  for (int e = t; e < c2*DIMS; e += 256) sums[e] = 0ull;
  for (int c = t; c < c2; c += 256) ndata[c] = 0u;
  if (t == 0) *distacc = 0ull;
}

// --- mean of x (LDS-tiled) + last block does init + split0 ---
__global__ void mean_kernel(const float* __restrict__ x, unsigned long long* __restrict__ macc,
                            float* __restrict__ cb, float* __restrict__ cnorm,
                            unsigned long long* __restrict__ sums,
                            unsigned int* __restrict__ ndata,
                            unsigned long long* __restrict__ distacc,
                            LbgState* __restrict__ st, unsigned int* __restrict__ mcnt){
  __shared__ double part[256];
  __shared__ float stage[16*64];
  __shared__ int islast;
  const int t = threadIdx.x;
  const int d = t & 63;
  const int w = t >> 6;
  const size_t base = (size_t)blockIdx.x * 1024;
  const int lrow = t >> 4;
  const int lcol = (t & 15) * 4;

  const float4* xg = reinterpret_cast<const float4*>(x);
  float4 nxt = xg[((base + lrow) * DIMS + lcol) >> 2];
  double s = 0.0;
  for (int tt = 0; tt < 64; tt++){
    float4 cur = nxt;
    if (tt < 63)
      nxt = xg[((base + (tt+1)*16 + lrow) * DIMS + lcol) >> 2];
    __syncthreads();
    *reinterpret_cast<float4*>(&stage[lrow*DIMS + lcol]) = cur;
    __syncthreads();
    s += (double)stage[(w    )*DIMS + d];
    s += (double)stage[(w + 4)*DIMS + d];
    s += (double)stage[(w + 8)*DIMS + d];
    s += (double)stage[(w +12)*DIMS + d];
  }
  part[t] = s;
  __syncthreads();
  if (t < 64){
    double tot = part[t] + part[64+t] + part[128+t] + part[192+t];
    atomicAdd(&macc[t], (unsigned long long)__double2ll_rn(tot * 1099511627776.0));
  }
  __threadfence();
  __syncthreads();
  if (t == 0) islast = (atomicAdd(mcnt, 1u) == (unsigned)(gridDim.x - 1));
  __syncthreads();
  if (!islast) return;

  if (t < 64){
    long long mv = (long long)atomicAdd(&macc[t], 0ull);
    double mean = (double)mv * (1.0/1099511627776.0) / 131072.0;
    cb[t] = (float)mean;
  }
  for (int e = t; e < KCB*DIMS; e += 256)
    if (e >= 64) cb[e] = 1e10f;
  if (t == 0){
    st->dist = __builtin_inff();
    st->prev = __builtin_inff();
    st->done = 0u;
    atomicExch(mcnt, 0u);
  }
  __syncthreads();
  do_split(cb, cnorm, sums, ndata, distacc, st, 1, 0, t);
}

// --- E-step for small CURR (<=32): one thread per point ---
template<int CURR>
__global__ __launch_bounds__(256, 4)
void estep_kernel(const float* __restrict__ x, const float* __restrict__ cb,
                  const float* __restrict__ cnorm, unsigned char* __restrict__ bidx8,
                  unsigned long long* __restrict__ distacc, const LbgState* __restrict__ st){
  if (st->done) return;
  const int t = threadIdx.x;
  const int lane = t & 63;
  const int p = blockIdx.x * 256 + t;

  float xv[DIMS];
  const float4* xp = reinterpret_cast<const float4*>(x + (size_t)p * DIMS);
  #pragma unroll
  for (int i = 0; i < 16; i++){
    float4 v = xp[i];
    xv[4*i+0] = v.x; xv[4*i+1] = v.y; xv[4*i+2] = v.z; xv[4*i+3] = v.w;
  }
  float xx = 0.f;
  #pragma unroll
  for (int d = 0; d < DIMS; d++) xx += xv[d] * xv[d];

  constexpr int NJ = (CURR < 4) ? CURR : 4;
  float best = __builtin_inff();
  int bi = 0;
  for (int j0 = 0; j0 < CURR; j0 += NJ){
    const float* crow = cb + (size_t)j0 * DIMS;
    float acc[NJ];
    #pragma unroll
    for (int k = 0; k < NJ; k++) acc[k] = 0.f;
    #pragma unroll
    for (int d = 0; d < DIMS; d++){
      #pragma unroll
      for (int k = 0; k < NJ; k++)
        acc[k] = fmaf(xv[d], crow[k*DIMS + d], acc[k]);
    }
    #pragma unroll
    for (int k = 0; k < NJ; k++){
      float d2 = (xx - 2.0f*acc[k]) + cnorm[j0 + k];
      if (d2 < best){ best = d2; bi = j0 + k; }
    }
  }
  bidx8[p] = (unsigned char)bi;

  double dd = 0.0;
  const float4* cbv = reinterpret_cast<const float4*>(cb + (size_t)bi * DIMS);
  #pragma unroll
  for (int i = 0; i < 16; i++){
    float4 b = cbv[i];
    float df, sq;
    df = xv[4*i+0] - b.x; sq = df*df; dd += (double)sq;
    df = xv[4*i+1] - b.y; sq = df*df; dd += (double)sq;
    df = xv[4*i+2] - b.z; sq = df*df; dd += (double)sq;
    df = xv[4*i+3] - b.w; sq = df*df; dd += (double)sq;
  }
  for (int off = 32; off > 0; off >>= 1) dd += __shfl_down(dd, off);
  if (lane == 0)
    atomicAdd(distacc, (unsigned long long)__double2ll_rn(dd * 4294967296.0));
}

// --- E-step CURR in {64,128,256}: 4p x 8c tile, 64-cw panels, register
// double-buffered k4 loop (prefetch next k4's xf/cf before current FMAs).
// FMA order per (cj,j) identical to R8/R11 => bitwise-identical d2.
template<int CURR>
__global__ __launch_bounds__(256, 3)
void estep_gemm(const float* __restrict__ x, const float* __restrict__ cb,
                const float* __restrict__ cnorm, unsigned char* __restrict__ bidx8,
                unsigned long long* __restrict__ distacc, const LbgState* __restrict__ st){
  if (st->done) return;
  constexpr int NPANEL = CURR / 64;
  __shared__ float4 xs[16*128];
  __shared__ float4 cbs[64*16];
  __shared__ float sxx[128];
  __shared__ unsigned char sbidx[128];
  const int t = threadIdx.x;
  const int pbase = blockIdx.x * 128;

  {
    const int p = t & 127, h = t >> 7;
    const float4* xg = reinterpret_cast<const float4*>(x) + (size_t)(pbase + p) * 16 + h * 8;
    #pragma unroll
    for (int j = 0; j < 8; j++)
      xs[(h*8 + j)*128 + p] = xg[j];
  }
  __syncthreads();
  if (t < 128){
    float xx = 0.f;
    #pragma unroll
    for (int k4 = 0; k4 < 16; k4++){
      float4 v = xs[k4*128 + t];
      xx = fmaf(v.x, v.x, xx); xx = fmaf(v.y, v.y, xx);
      xx = fmaf(v.z, v.z, xx); xx = fmaf(v.w, v.w, xx);
    }
    sxx[t] = xx;
  }
  __syncthreads();

  const int cg = t & 7;
  const int pg = t >> 3;
  float best[4] = {__builtin_inff(), __builtin_inff(), __builtin_inff(), __builtin_inff()};
  int bidx[4] = {0,0,0,0};
  float xxv[4];
  #pragma unroll
  for (int j = 0; j < 4; j++) xxv[j] = sxx[pg + 32*j];

  const float4* cbg = reinterpret_cast<const float4*>(cb);
  for (int panel = 0; panel < NPANEL; panel++){
    __syncthreads();
    for (int idx = t; idx < 1024; idx += 256){
      const int cl = idx >> 4, kk = idx & 15;
      cbs[cl*16 + (kk ^ (cl >> 3))] = cbg[(size_t)(panel*64 + cl)*16 + kk];
    }
    __syncthreads();

    const int c0 = panel*64 + cg*8;
    float acc[4][8];
    #pragma unroll
    for (int j = 0; j < 4; j++)
      #pragma unroll
      for (int cj = 0; cj < 8; cj++) acc[j][cj] = 0.f;

    // register double-buffer: prefetch k4+1's operands before k4's FMAs
    float4 xfA[4], cfA[8], xfB[4], cfB[8];
    #pragma unroll
    for (int j = 0; j < 4; j++) xfA[j] = xs[pg + 32*j];            // k4=0
    #pragma unroll
    for (int cj = 0; cj < 8; cj++) cfA[cj] = cbs[(cg*8 + cj)*16 + cg]; // k4=0: 0^cg=cg

    #pragma unroll
    for (int k4 = 0; k4 < 16; k4++){
      if (k4 < 15){
        #pragma unroll
        for (int j = 0; j < 4; j++) xfB[j] = xs[(k4+1)*128 + pg + 32*j];
        #pragma unroll
        for (int cj = 0; cj < 8; cj++) cfB[cj] = cbs[(cg*8 + cj)*16 + ((k4+1) ^ cg)];
      }
      #pragma unroll
      for (int cj = 0; cj < 8; cj++){
        float4 cf = cfA[cj];
        #pragma unroll
        for (int j = 0; j < 4; j++){
          acc[j][cj] = fmaf(xfA[j].x, cf.x, acc[j][cj]);
          acc[j][cj] = fmaf(xfA[j].y, cf.y, acc[j][cj]);
          acc[j][cj] = fmaf(xfA[j].z, cf.z, acc[j][cj]);
          acc[j][cj] = fmaf(xfA[j].w, cf.w, acc[j][cj]);
        }
      }
      #pragma unroll
      for (int j = 0; j < 4; j++) xfA[j] = xfB[j];
      #pragma unroll
      for (int cj = 0; cj < 8; cj++) cfA[cj] = cfB[cj];
    }
    #pragma unroll
    for (int cj = 0; cj < 8; cj++){
      float cn = cnorm[c0 + cj];
      #pragma unroll
      for (int j = 0; j < 4; j++){
        float d2 = (xxv[j] - 2.0f*acc[j][cj]) + cn;
        if (d2 < best[j]){ best[j] = d2; bidx[j] = c0 + cj; }
      }
    }
  }
  #pragma unroll
  for (int m = 1; m < 8; m <<= 1){
    #pragma unroll
    for (int j = 0; j < 4; j++){
      float ob = __shfl_xor(best[j], m, 64);
      int   oc = __shfl_xor(bidx[j], m, 64);
      if (ob < best[j] || (ob == best[j] && oc < bidx[j])){ best[j] = ob; bidx[j] = oc; }
    }
  }
  if (cg == 0){
    #pragma unroll
    for (int j = 0; j < 4; j++) sbidx[pg + 32*j] = (unsigned char)bidx[j];
  }
  __syncthreads();
  if (t < 128){
    const int bi = (int)sbidx[t];
    bidx8[pbase + t] = (unsigned char)bi;
    const float4* cbv = cbg + (size_t)bi * 16;
    double dd = 0.0;
    #pragma unroll
    for (int k4 = 0; k4 < 16; k4++){
      float4 xv = xs[k4*128 + t];
      float4 b = cbv[k4];
      float df, sq;
      df = xv.x - b.x; sq = df*df; dd += (double)sq;
      df = xv.y - b.y; sq = df*df; dd += (double)sq;
      df = xv.z - b.z; sq = df*df; dd += (double)sq;
      df = xv.w - b.w; sq = df*df; dd += (double)sq;
    }
    for (int off = 32; off > 0; off >>= 1) dd += __shfl_down(dd, off);
    if ((t & 63) == 0)
      atomicAdd(distacc, (unsigned long long)__double2ll_rn(dd * 4294967296.0));
  }
}

// --- Gather (R8): ballot-harvest with 4-deep load queue ---
template<int CURR, int NBLK>
__global__ __launch_bounds__(256)
void gather_kernel(const float* __restrict__ x, const unsigned char* __restrict__ bidx8,
                   unsigned long long* __restrict__ sums, unsigned int* __restrict__ ndata,
                   const LbgState* __restrict__ st){
  if (st->done) return;
  constexpr int CLOG = __builtin_ctz(CURR);
  constexpr int NCHUNK = NBLK / CURR;
  constexpr int PPC = NPTS / NCHUNK;
  constexpr int NPW = PPC / 4;
  __shared__ long long sacc[4*64];
  __shared__ unsigned int scw[4];
  const int t = threadIdx.x;
  const int lane = t & 63;
  const int w = t >> 6;
  const int c = blockIdx.x & (CURR - 1);
  const int chunk = blockIdx.x >> CLOG;
  const int pbase = chunk * PPC + w * NPW;

  long long acc = 0;
  unsigned int cnt = 0;
  int q0 = 0, q1 = 0, q2 = 0, q3 = 0, qn = 0;
  const uint32_t* bp = reinterpret_cast<const uint32_t*>(bidx8 + pbase);
  for (int i = 0; i < NPW; i += 256){
    const uint32_t b4 = bp[(i >> 2) + lane];
    #pragma unroll
    for (int s = 0; s < 4; s++){
      unsigned long long m = __ballot(((b4 >> (8*s)) & 255u) == (unsigned)c);
      cnt += (unsigned int)__popcll(m);
      while (m){
        const int bit = __builtin_ctzll(m);
        m &= m - 1ull;
        const int p = pbase + i + bit*4 + s;
        if      (qn == 0) q0 = p;
        else if (qn == 1) q1 = p;
        else if (qn == 2) q2 = p;
        else              q3 = p;
        qn++;
        if (qn == 4){
          const float v0 = x[(size_t)q0 * DIMS + lane];
          const float v1 = x[(size_t)q1 * DIMS + lane];
          const float v2 = x[(size_t)q2 * DIMS + lane];
          const float v3 = x[(size_t)q3 * DIMS + lane];
          acc += (long long)__double2int_rn((double)v0 * 1048576.0);
          acc += (long long)__double2int_rn((double)v1 * 1048576.0);
          acc += (long long)__double2int_rn((double)v2 * 1048576.0);
          acc += (long long)__double2int_rn((double)v3 * 1048576.0);
          qn = 0;
        }
      }
    }
  }
  if (qn > 0){
    const int i1 = (qn > 1) ? q1 : q0;
    const int i2 = (qn > 2) ? q2 : q0;
    const float v0 = x[(size_t)q0 * DIMS + lane];
    const float v1 = x[(size_t)i1 * DIMS + lane];
    const float v2 = x[(size_t)i2 * DIMS + lane];
    acc += (long long)__double2int_rn((double)v0 * 1048576.0);
    if (qn > 1) acc += (long long)__double2int_rn((double)v1 * 1048576.0);
    if (qn > 2) acc += (long long)__double2int_rn((double)v2 * 1048576.0);
  }
  sacc[w*64 + lane] = acc;
  if (lane == 0) scw[w] = cnt;
  __syncthreads();
  if (w == 0){
    long long tot = sacc[lane] + sacc[64+lane] + sacc[128+lane] + sacc[192+lane];
    if (tot) atomicAdd(&sums[c*DIMS + lane], (unsigned long long)(tot * 1048576ll));
    if (lane == 0){
      unsigned int ct = scw[0] + scw[1] + scw[2] + scw[3];
      if (ct) atomicAdd(&ndata[c], ct);
    }
  }
}

// --- convergence + M-step finalize + (n==4) split/finalize (one block) ---
__global__ void control_kernel(float* __restrict__ cb, float* __restrict__ cnorm,
                               unsigned long long* __restrict__ sums,
                               unsigned int* __restrict__ ndata,
                               unsigned long long* __restrict__ distacc,
                               LbgState* __restrict__ st, int curr, int n_iter,
                               int next_split){
  __shared__ int s_stop;
  __shared__ unsigned int sdone;
  __shared__ uint32_t sub0, sub1;
  __shared__ float cm[64];
  __shared__ int redv[256];
  __shared__ int redi[256];
  __shared__ int s_m, s_cnt;
  const int t = threadIdx.x;
  if (t == 0) sdone = st->done;
  __syncthreads();
  const unsigned int done0 = sdone;

  if (!done0){
    if (t == 0){
      double dd = (double)(long long)(*distacc) * (1.0/4294967296.0);
      float sf = (float)dd;
      float d_new = sf / 131072.0f;
      float change = fabsf(st->prev - d_new);
      int conv = (n_iter > 0) && (change / (d_new + 1e-16f) < 1e-5f);
      st->dist = d_new;
      if (!conv) st->prev = d_new;
      st->done = conv ? 1u : 0u;
      s_stop = conv;
      if (!conv){
        uint32_t a0, a1, b0, b1;
        tf2x32(st->k0, st->k1, 0u, 0u, a0, a1);
        tf2x32(st->k0, st->k1, 0u, 1u, b0, b1);
        st->k0 = a0; st->k1 = a1;
        sub0 = b0; sub1 = b1;
      }
    }
    __syncthreads();
    if (!s_stop){
      int v = (t < curr) ? (int)ndata[t] : -1;
      redv[t] = v; redi[t] = t;
      __syncthreads();
      for (int s = 128; s > 0; s >>= 1){
        if (t < s){
          if (redv[t+s] > redv[t] || (redv[t+s] == redv[t] && redi[t+s] < redi[t])){
            redv[t] = redv[t+s]; redi[t] = redi[t+s];
          }
        }
        __syncthreads();
      }
      if (t == 0) s_m = redi[0];
      __syncthreads();
      redv[t] = (t < curr && ndata[t] == 0u) ? 1 : 0;
      __syncthreads();
      for (int s = 128; s > 0; s >>= 1){
        if (t < s) redv[t] += redv[t+s];
        __syncthreads();
      }
      if (t == 0) s_cnt = redv[0];
      __syncthreads();
      const int m = s_m;
      const int cntE = s_cnt;

      if (t < 64){
        unsigned int nm_ = ndata[m]; if (nm_ < 1u) nm_ = 1u;
        double cd = (double)(long long)sums[m*DIMS + t] * (1.0/1099511627776.0) / (double)nm_;
        cm[t] = (float)cd;
      }
      __syncthreads();

      const int total = curr * DIMS;
      for (int e = t; e < total; e += 256){
        int c = e >> 6, d = e & 63;
        if (c == m) continue;
        float nv;
        unsigned int nd = ndata[c];
        if (nd >= 1u){
          double cd = (double)(long long)sums[e] * (1.0/1099511627776.0) / (double)nd;
          nv = (float)cd;
        } else {
          float rv = jax_normal_elem(sub0, sub1, (uint32_t)e) * 1e-5f;
          nv = cm[d] - rv;
        }
        cb[e] = nv;
      }
      if (t < 64){
        float add = 0.f;
        if (cntE > 0){
          float acc = 0.f;
          for (int c = 0; c < curr; c++){
            if (ndata[c] == 0u)
              acc += jax_normal_elem(sub0, sub1, (uint32_t)(c*DIMS + t)) * 1e-5f;
          }
          add = acc / fmaxf((float)cntE, 1.0f);
        }
        cb[m*DIMS + t] = cm[t] + add;
      }
      __syncthreads();

      for (int c = t; c < curr; c += 256){
        float s = 0.f;
        for (int d = 0; d < DIMS; d++){ float vv = cb[c*DIMS+d]; s += vv*vv; }
        cnorm[c] = s;
      }
      for (int e = t; e < total; e += 256) sums[e] = 0ull;
      for (int c = t; c < curr; c += 256) ndata[c] = 0u;
      if (t == 0) *distacc = 0ull;
    }
  }
  __syncthreads();
  if (n_iter == 4){
    if (curr < 256){
      do_split(cb, cnorm, sums, ndata, distacc, st, curr, next_split, t);
    } else if (t == 0){
      cb[KCB*DIMS] = st->dist;               // finalize: out[16384] = distance
    }
  }
}

extern "C" void kernel_launch(void* const* d_in, const int* in_sizes, int n_in,
                              void* d_out, int out_size, void* d_ws, size_t ws_size,
                              hipStream_t stream){
  const float* x = (const float*)d_in[0];
  float* cb = (float*)d_out;
  char* ws = (char*)d_ws;
  unsigned long long* sums    = (unsigned long long*)(ws + 0);        // 131072 B
  unsigned long long* macc    = (unsigned long long*)(ws + 131072);   // 512 B
  unsigned long long* distacc = (unsigned long long*)(ws + 131584);   // 8 B
  LbgState* st                = (LbgState*)(ws + 131592);             // 24 B
  unsigned int* ndata         = (unsigned int*)(ws + 131616);         // 1024 B
  float* cnorm                = (float*)(ws + 132640);                // 1024 B
  unsigned char* bidx8        = (unsigned char*)(ws + 133664);        // 131072 B
  unsigned int* mcnt          = (unsigned int*)(ws + 264736);         // 4 B

  hipMemsetAsync(d_ws, 0, 264744, stream);
  mean_kernel<<<128, 256, 0, stream>>>(x, macc, cb, cnorm, sums, ndata, distacc, st, mcnt);

  for (int split = 0; split < 8; split++){
    const int curr = 2 << split;
    for (int n = 0; n < 5; n++){
      switch (curr){
        case 2:   estep_kernel<2>  <<<512,256,0,stream>>>(x,cb,cnorm,bidx8,distacc,st);
                  gather_kernel<2,256>   <<<256, 256,0,stream>>>(x,bidx8,sums,ndata,st); break;
        case 4:   estep_kernel<4>  <<<512,256,0,stream>>>(x,cb,cnorm,bidx8,distacc,st);
                  gather_kernel<4,512>   <<<512, 256,0,stream>>>(x,bidx8,sums,ndata,st); break;
        case 8:   estep_kernel<8>  <<<512,256,0,stream>>>(x,cb,cnorm,bidx8,distacc,st);
                  gather_kernel<8,512>   <<<512, 256,0,stream>>>(x,bidx8,sums,ndata,st); break;
        case 16:  estep_kernel<16> <<<512,256,0,stream>>>(x,cb,cnorm,bidx8,distacc,st);
                  gather_kernel<16,512>  <<<512, 256,0,stream>>>(x,bidx8,sums,ndata,st); break;
        case 32:  estep_kernel<32> <<<512,256,0,stream>>>(x,cb,cnorm,bidx8,distacc,st);
                  gather_kernel<32,512>  <<<512, 256,0,stream>>>(x,bidx8,sums,ndata,st); break;
        case 64:  estep_gemm<64>  <<<1024,256,0,stream>>>(x,cb,cnorm,bidx8,distacc,st);
                  gather_kernel<64,512>  <<<512, 256,0,stream>>>(x,bidx8,sums,ndata,st); break;
        case 128: estep_gemm<128> <<<1024,256,0,stream>>>(x,cb,cnorm,bidx8,distacc,st);
                  gather_kernel<128,1024><<<1024,256,0,stream>>>(x,bidx8,sums,ndata,st); break;
        case 256: estep_gemm<256> <<<1024,256,0,stream>>>(x,cb,cnorm,bidx8,distacc,st);
                  gather_kernel<256,2048><<<2048,256,0,stream>>>(x,bidx8,sums,ndata,st); break;
      }
      control_kernel<<<1, 256, 0, stream>>>(cb, cnorm, sums, ndata, distacc, st, curr, n, split+1);
    }
  }
}

// Round 13
// 3222.820 us; speedup vs baseline: 5.0647x; 1.1204x over previous
//
#include <hip/hip_runtime.h>
#include <stdint.h>

// LBG vector quantization, bit-faithful port of the JAX ref.
// Round 13: base = R8 (best, 3.33 ms). estep for CURR>=64 rewritten as
// "scalar-wave" GEMM: wave w owns a uniform CURR/4 codeword stripe -> cb
// loads become s_load_dwordx4 (scalar cache, no LDS pipe); thread = 2 pts
// x 8 cw; LDS = x tile only (37.5 KB -> 4 blocks/CU). R12's register
// double-buffer (scratch-spilled, 166 MB WRITE) reverted.
// Per-(point,cw) fma chains and argmin semantics unchanged =>
// bit-identical trajectory (absmax 0.4985352).

#define NPTS 131072
#define DIMS 64
#define KCB  256

struct LbgState { float dist; float prev; unsigned int done; unsigned int k0, k1; unsigned int pad; };

__device__ __forceinline__ uint32_t rotl32(uint32_t v, int n){ return (v<<n)|(v>>(32-n)); }

// Threefry-2x32, 20 rounds (matches jax._src.prng.threefry2x32)
__device__ __forceinline__ void tf2x32(uint32_t k0, uint32_t k1, uint32_t x0, uint32_t x1,
                                       uint32_t& o0, uint32_t& o1){
  uint32_t ks2 = k0 ^ k1 ^ 0x1BD11BDAu;
  x0 += k0; x1 += k1;
  #define TFR(r) { x0 += x1; x1 = rotl32(x1, r); x1 ^= x0; }
  TFR(13) TFR(15) TFR(26) TFR(6)
  x0 += k1; x1 += ks2 + 1u;
  TFR(17) TFR(29) TFR(16) TFR(24)
  x0 += ks2; x1 += k0 + 2u;
  TFR(13) TFR(15) TFR(26) TFR(6)
  x0 += k0; x1 += k1 + 3u;
  TFR(17) TFR(29) TFR(16) TFR(24)
  x0 += k1; x1 += ks2 + 4u;
  TFR(13) TFR(15) TFR(26) TFR(6)
  x0 += ks2; x1 += k0 + 5u;
  #undef TFR
  o0 = x0; o1 = x1;
}

// XLA ErfInv (f32, Giles polynomial)
__device__ __forceinline__ float xla_erfinv_f32(float x){
  float w = -log1pf(-x*x);
  float p;
  if (w < 5.0f){
    w = w - 2.5f;
    p = 2.81022636e-08f;
    p = fmaf(p, w, 3.43273939e-07f);
    p = fmaf(p, w, -3.5233877e-06f);
    p = fmaf(p, w, -4.39150654e-06f);
    p = fmaf(p, w, 0.00021858087f);
    p = fmaf(p, w, -0.00125372503f);
    p = fmaf(p, w, -0.00417768164f);
    p = fmaf(p, w, 0.246640727f);
    p = fmaf(p, w, 1.50140941f);
  } else {
    w = sqrtf(w) - 3.0f;
    p = -0.000200214257f;
    p = fmaf(p, w, 0.000100950558f);
    p = fmaf(p, w, 0.00134934322f);
    p = fmaf(p, w, -0.00367342844f);
    p = fmaf(p, w, 0.00573950773f);
    p = fmaf(p, w, -0.0076224613f);
    p = fmaf(p, w, 0.00943887047f);
    p = fmaf(p, w, 1.00167406f);
    p = fmaf(p, w, 2.83297682f);
  }
  return p * x;
}

__device__ __forceinline__ float jax_normal_elem(uint32_t k0, uint32_t k1, uint32_t j){
  uint32_t o0, o1; tf2x32(k0, k1, 0u, j, o0, o1);
  uint32_t bits = o0 ^ o1;
  uint32_t fb = (bits >> 9) | 0x3f800000u;
  float f = __uint_as_float(fb) - 1.0f;
  const float lo = -0.99999994f;
  float u = f * 2.0f + lo;
  u = fmaxf(lo, u);
  return 1.41421356f * xla_erfinv_f32(u);
}

// --- split phase (used by mean last-block for split0 and control at n==4) ---
__device__ void do_split(float* __restrict__ cb, float* __restrict__ cnorm,
                         unsigned long long* __restrict__ sums,
                         unsigned int* __restrict__ ndata,
                         unsigned long long* __restrict__ distacc,
                         LbgState* __restrict__ st, int curr, int split, int t){
  __shared__ uint32_t kr0s, kr1s;
  if (t == 0){
    uint32_t ks0, ks1, a0, a1, b0, b1;
    tf2x32(0u, 42u, 0u, (uint32_t)split, ks0, ks1);
    tf2x32(ks0, ks1, 0u, 0u, a0, a1);
    tf2x32(ks0, ks1, 0u, 1u, b0, b1);
    kr0s = a0; kr1s = a1;
    st->k0 = b0; st->k1 = b1;
    st->prev = st->dist;
    st->done = 0u;
  }
  __syncthreads();
  const int n = curr * DIMS;
  for (int e = t; e < n; e += 256){
    int c = e >> 6, d = e & 63;
    float rv = jax_normal_elem(kr0s, kr1s, (uint32_t)e) * 1e-5f;
    float old = cb[c*DIMS + d];
    cb[(curr + c)*DIMS + d] = old - rv;
    cb[c*DIMS + d]          = old + rv;
  }
  __syncthreads();
  const int c2 = curr * 2;
  for (int c = t; c < c2; c += 256){
    float s = 0.f;
    for (int d = 0; d < DIMS; d++){ float vv = cb[c*DIMS+d]; s += vv*vv; }
    cnorm[c] = s;
  }
  for (int e = t; e < c2*DIMS; e += 256) sums[e] = 0ull;
  for (int c = t; c < c2; c += 256) ndata[c] = 0u;
  if (t == 0) *distacc = 0ull;
}

// --- mean of x (LDS-tiled) + last block does init + split0 ---
__global__ void mean_kernel(const float* __restrict__ x, unsigned long long* __restrict__ macc,
                            float* __restrict__ cb, float* __restrict__ cnorm,
                            unsigned long long* __restrict__ sums,
                            unsigned int* __restrict__ ndata,
                            unsigned long long* __restrict__ distacc,
                            LbgState* __restrict__ st, unsigned int* __restrict__ mcnt){
  __shared__ double part[256];
  __shared__ float stage[16*64];
  __shared__ int islast;
  const int t = threadIdx.x;
  const int d = t & 63;
  const int w = t >> 6;
  const size_t base = (size_t)blockIdx.x * 1024;
  const int lrow = t >> 4;
  const int lcol = (t & 15) * 4;

  const float4* xg = reinterpret_cast<const float4*>(x);
  float4 nxt = xg[((base + lrow) * DIMS + lcol) >> 2];
  double s = 0.0;
  for (int tt = 0; tt < 64; tt++){
    float4 cur = nxt;
    if (tt < 63)
      nxt = xg[((base + (tt+1)*16 + lrow) * DIMS + lcol) >> 2];
    __syncthreads();
    *reinterpret_cast<float4*>(&stage[lrow*DIMS + lcol]) = cur;
    __syncthreads();
    s += (double)stage[(w    )*DIMS + d];
    s += (double)stage[(w + 4)*DIMS + d];
    s += (double)stage[(w + 8)*DIMS + d];
    s += (double)stage[(w +12)*DIMS + d];
  }
  part[t] = s;
  __syncthreads();
  if (t < 64){
    double tot = part[t] + part[64+t] + part[128+t] + part[192+t];
    atomicAdd(&macc[t], (unsigned long long)__double2ll_rn(tot * 1099511627776.0));
  }
  __threadfence();
  __syncthreads();
  if (t == 0) islast = (atomicAdd(mcnt, 1u) == (unsigned)(gridDim.x - 1));
  __syncthreads();
  if (!islast) return;

  if (t < 64){
    long long mv = (long long)atomicAdd(&macc[t], 0ull);
    double mean = (double)mv * (1.0/1099511627776.0) / 131072.0;
    cb[t] = (float)mean;
  }
  for (int e = t; e < KCB*DIMS; e += 256)
    if (e >= 64) cb[e] = 1e10f;
  if (t == 0){
    st->dist = __builtin_inff();
    st->prev = __builtin_inff();
    st->done = 0u;
    atomicExch(mcnt, 0u);
  }
  __syncthreads();
  do_split(cb, cnorm, sums, ndata, distacc, st, 1, 0, t);
}

// --- E-step for small CURR (<=32): one thread per point ---
template<int CURR>
__global__ __launch_bounds__(256, 4)
void estep_kernel(const float* __restrict__ x, const float* __restrict__ cb,
                  const float* __restrict__ cnorm, unsigned char* __restrict__ bidx8,
                  unsigned long long* __restrict__ distacc, const LbgState* __restrict__ st){
  if (st->done) return;
  const int t = threadIdx.x;
  const int lane = t & 63;
  const int p = blockIdx.x * 256 + t;

  float xv[DIMS];
  const float4* xp = reinterpret_cast<const float4*>(x + (size_t)p * DIMS);
  #pragma unroll
  for (int i = 0; i < 16; i++){
    float4 v = xp[i];
    xv[4*i+0] = v.x; xv[4*i+1] = v.y; xv[4*i+2] = v.z; xv[4*i+3] = v.w;
  }
  float xx = 0.f;
  #pragma unroll
  for (int d = 0; d < DIMS; d++) xx += xv[d] * xv[d];

  constexpr int NJ = (CURR < 4) ? CURR : 4;
  float best = __builtin_inff();
  int bi = 0;
  for (int j0 = 0; j0 < CURR; j0 += NJ){
    const float* crow = cb + (size_t)j0 * DIMS;
    float acc[NJ];
    #pragma unroll
    for (int k = 0; k < NJ; k++) acc[k] = 0.f;
    #pragma unroll
    for (int d = 0; d < DIMS; d++){
      #pragma unroll
      for (int k = 0; k < NJ; k++)
        acc[k] = fmaf(xv[d], crow[k*DIMS + d], acc[k]);
    }
    #pragma unroll
    for (int k = 0; k < NJ; k++){
      float d2 = (xx - 2.0f*acc[k]) + cnorm[j0 + k];
      if (d2 < best){ best = d2; bi = j0 + k; }
    }
  }
  bidx8[p] = (unsigned char)bi;

  double dd = 0.0;
  const float4* cbv = reinterpret_cast<const float4*>(cb + (size_t)bi * DIMS);
  #pragma unroll
  for (int i = 0; i < 16; i++){
    float4 b = cbv[i];
    float df, sq;
    df = xv[4*i+0] - b.x; sq = df*df; dd += (double)sq;
    df = xv[4*i+1] - b.y; sq = df*df; dd += (double)sq;
    df = xv[4*i+2] - b.z; sq = df*df; dd += (double)sq;
    df = xv[4*i+3] - b.w; sq = df*df; dd += (double)sq;
  }
  for (int off = 32; off > 0; off >>= 1) dd += __shfl_down(dd, off);
  if (lane == 0)
    atomicAdd(distacc, (unsigned long long)__double2ll_rn(dd * 4294967296.0));
}

// --- E-step CURR>=64 "scalar-wave": wave w owns cw stripe [w*CURR/4, ...),
// cb/cnorm loads are wave-uniform -> s_load (scalar cache, no LDS/vector
// pressure). Thread = 2 points x 8 cw. LDS = x tile only (4 blocks/CU).
// Per-(p,cw) fma chain: k4 ascending, x/y/z/w -> bitwise == R8.
// Argmin: per-wave ascending scan + cross-wave ascending combine (strict <)
// == global first-min. Dist epilogue verbatim R8.
template<int CURR>
__global__ __launch_bounds__(256, 4)
void estep_sw(const float* __restrict__ x, const float* __restrict__ cb,
              const float* __restrict__ cnorm, unsigned char* __restrict__ bidx8,
              unsigned long long* __restrict__ distacc, const LbgState* __restrict__ st){
  if (st->done) return;
  constexpr int CPW = CURR / 4;          // codewords per wave
  constexpr int NG = CPW / 8;            // cw-groups of 8
  __shared__ float4 xs[16*128];          // 32 KB
  __shared__ float sxx[128];
  __shared__ float sbest[4*128];
  __shared__ int   sidx [4*128];
  __shared__ unsigned char sbidx[128];
  const int t = threadIdx.x;
  const int lane = t & 63;
  const int w = __builtin_amdgcn_readfirstlane(t >> 6);
  const int pbase = blockIdx.x * 128;

  { // stage x tile k-major
    const int p = t & 127, h = t >> 7;
    const float4* xg = reinterpret_cast<const float4*>(x) + (size_t)(pbase + p) * 16 + h * 8;
    #pragma unroll
    for (int j = 0; j < 8; j++)
      xs[(h*8 + j)*128 + p] = xg[j];
  }
  __syncthreads();
  if (t < 128){
    float xx = 0.f;
    #pragma unroll
    for (int k4 = 0; k4 < 16; k4++){
      float4 v = xs[k4*128 + t];
      xx = fmaf(v.x, v.x, xx); xx = fmaf(v.y, v.y, xx);
      xx = fmaf(v.z, v.z, xx); xx = fmaf(v.w, v.w, xx);
    }
    sxx[t] = xx;
  }
  __syncthreads();

  const float xx0 = sxx[lane];
  const float xx1 = sxx[64 + lane];
  float best0 = __builtin_inff(), best1 = __builtin_inff();
  int bi0 = 0, bi1 = 0;
  const float4* cbg = reinterpret_cast<const float4*>(cb);
  const int cwbase = w * CPW;

  for (int g = 0; g < NG; g++){
    const int c0 = cwbase + g*8;
    float acc0[8], acc1[8];
    #pragma unroll
    for (int cj = 0; cj < 8; cj++){ acc0[cj] = 0.f; acc1[cj] = 0.f; }
    for (int k4 = 0; k4 < 16; k4++){
      float4 xf0 = xs[k4*128 + lane];
      float4 xf1 = xs[k4*128 + 64 + lane];
      #pragma unroll
      for (int cj = 0; cj < 8; cj++){
        float4 cf = cbg[(size_t)(c0 + cj)*16 + k4];   // wave-uniform -> s_load
        acc0[cj] = fmaf(xf0.x, cf.x, acc0[cj]);
        acc0[cj] = fmaf(xf0.y, cf.y, acc0[cj]);
        acc0[cj] = fmaf(xf0.z, cf.z, acc0[cj]);
        acc0[cj] = fmaf(xf0.w, cf.w, acc0[cj]);
        acc1[cj] = fmaf(xf1.x, cf.x, acc1[cj]);
        acc1[cj] = fmaf(xf1.y, cf.y, acc1[cj]);
        acc1[cj] = fmaf(xf1.z, cf.z, acc1[cj]);
        acc1[cj] = fmaf(xf1.w, cf.w, acc1[cj]);
      }
    }
    #pragma unroll
    for (int cj = 0; cj < 8; cj++){
      float cn = cnorm[c0 + cj];                      // wave-uniform -> s_load
      float d20 = (xx0 - 2.0f*acc0[cj]) + cn;
      if (d20 < best0){ best0 = d20; bi0 = c0 + cj; } // ascending c within wave
      float d21 = (xx1 - 2.0f*acc1[cj]) + cn;
      if (d21 < best1){ best1 = d21; bi1 = c0 + cj; }
    }
  }
  sbest[w*128 + lane]      = best0;  sidx[w*128 + lane]      = bi0;
  sbest[w*128 + 64 + lane] = best1;  sidx[w*128 + 64 + lane] = bi1;
  __syncthreads();

  if (t < 128){
    float best = sbest[t];
    int bi = sidx[t];
    #pragma unroll
    for (int ww = 1; ww < 4; ww++){                   // ascending cw ranges
      float ob = sbest[ww*128 + t];
      int   oi = sidx [ww*128 + t];
      if (ob < best){ best = ob; bi = oi; }           // strict < keeps lowest
    }
    sbidx[t] = (unsigned char)bi;
    bidx8[pbase + t] = (unsigned char)bi;
    const float4* cbv = cbg + (size_t)bi * 16;
    double dd = 0.0;
    #pragma unroll
    for (int k4 = 0; k4 < 16; k4++){
      float4 xv = xs[k4*128 + t];
      float4 b = cbv[k4];
      float df, sq;
      df = xv.x - b.x; sq = df*df; dd += (double)sq;
      df = xv.y - b.y; sq = df*df; dd += (double)sq;
      df = xv.z - b.z; sq = df*df; dd += (double)sq;
      df = xv.w - b.w; sq = df*df; dd += (double)sq;
    }
    for (int off = 32; off > 0; off >>= 1) dd += __shfl_down(dd, off);
    if ((t & 63) == 0)
      atomicAdd(distacc, (unsigned long long)__double2ll_rn(dd * 4294967296.0));
  }
}

// --- Gather (R8): ballot-harvest with 4-deep load queue ---
template<int CURR, int NBLK>
__global__ __launch_bounds__(256)
void gather_kernel(const float* __restrict__ x, const unsigned char* __restrict__ bidx8,
                   unsigned long long* __restrict__ sums, unsigned int* __restrict__ ndata,
                   const LbgState* __restrict__ st){
  if (st->done) return;
  constexpr int CLOG = __builtin_ctz(CURR);
  constexpr int NCHUNK = NBLK / CURR;
  constexpr int PPC = NPTS / NCHUNK;
  constexpr int NPW = PPC / 4;
  __shared__ long long sacc[4*64];
  __shared__ unsigned int scw[4];
  const int t = threadIdx.x;
  const int lane = t & 63;
  const int w = t >> 6;
  const int c = blockIdx.x & (CURR - 1);
  const int chunk = blockIdx.x >> CLOG;
  const int pbase = chunk * PPC + w * NPW;

  long long acc = 0;
  unsigned int cnt = 0;
  int q0 = 0, q1 = 0, q2 = 0, q3 = 0, qn = 0;
  const uint32_t* bp = reinterpret_cast<const uint32_t*>(bidx8 + pbase);
  for (int i = 0; i < NPW; i += 256){
    const uint32_t b4 = bp[(i >> 2) + lane];
    #pragma unroll
    for (int s = 0; s < 4; s++){
      unsigned long long m = __ballot(((b4 >> (8*s)) & 255u) == (unsigned)c);
      cnt += (unsigned int)__popcll(m);
      while (m){
        const int bit = __builtin_ctzll(m);
        m &= m - 1ull;
        const int p = pbase + i + bit*4 + s;
        if      (qn == 0) q0 = p;
        else if (qn == 1) q1 = p;
        else if (qn == 2) q2 = p;
        else              q3 = p;
        qn++;
        if (qn == 4){
          const float v0 = x[(size_t)q0 * DIMS + lane];
          const float v1 = x[(size_t)q1 * DIMS + lane];
          const float v2 = x[(size_t)q2 * DIMS + lane];
          const float v3 = x[(size_t)q3 * DIMS + lane];
          acc += (long long)__double2int_rn((double)v0 * 1048576.0);
          acc += (long long)__double2int_rn((double)v1 * 1048576.0);
          acc += (long long)__double2int_rn((double)v2 * 1048576.0);
          acc += (long long)__double2int_rn((double)v3 * 1048576.0);
          qn = 0;
        }
      }
    }
  }
  if (qn > 0){
    const int i1 = (qn > 1) ? q1 : q0;
    const int i2 = (qn > 2) ? q2 : q0;
    const float v0 = x[(size_t)q0 * DIMS + lane];
    const float v1 = x[(size_t)i1 * DIMS + lane];
    const float v2 = x[(size_t)i2 * DIMS + lane];
    acc += (long long)__double2int_rn((double)v0 * 1048576.0);
    if (qn > 1) acc += (long long)__double2int_rn((double)v1 * 1048576.0);
    if (qn > 2) acc += (long long)__double2int_rn((double)v2 * 1048576.0);
  }
  sacc[w*64 + lane] = acc;
  if (lane == 0) scw[w] = cnt;
  __syncthreads();
  if (w == 0){
    long long tot = sacc[lane] + sacc[64+lane] + sacc[128+lane] + sacc[192+lane];
    if (tot) atomicAdd(&sums[c*DIMS + lane], (unsigned long long)(tot * 1048576ll));
    if (lane == 0){
      unsigned int ct = scw[0] + scw[1] + scw[2] + scw[3];
      if (ct) atomicAdd(&ndata[c], ct);
    }
  }
}

// --- convergence + M-step finalize + (n==4) split/finalize (one block) ---
__global__ void control_kernel(float* __restrict__ cb, float* __restrict__ cnorm,
                               unsigned long long* __restrict__ sums,
                               unsigned int* __restrict__ ndata,
                               unsigned long long* __restrict__ distacc,
                               LbgState* __restrict__ st, int curr, int n_iter,
                               int next_split){
  __shared__ int s_stop;
  __shared__ unsigned int sdone;
  __shared__ uint32_t sub0, sub1;
  __shared__ float cm[64];
  __shared__ int redv[256];
  __shared__ int redi[256];
  __shared__ int s_m, s_cnt;
  const int t = threadIdx.x;
  if (t == 0) sdone = st->done;
  __syncthreads();
  const unsigned int done0 = sdone;

  if (!done0){
    if (t == 0){
      double dd = (double)(long long)(*distacc) * (1.0/4294967296.0);
      float sf = (float)dd;
      float d_new = sf / 131072.0f;
      float change = fabsf(st->prev - d_new);
      int conv = (n_iter > 0) && (change / (d_new + 1e-16f) < 1e-5f);
      st->dist = d_new;
      if (!conv) st->prev = d_new;
      st->done = conv ? 1u : 0u;
      s_stop = conv;
      if (!conv){
        uint32_t a0, a1, b0, b1;
        tf2x32(st->k0, st->k1, 0u, 0u, a0, a1);
        tf2x32(st->k0, st->k1, 0u, 1u, b0, b1);
        st->k0 = a0; st->k1 = a1;
        sub0 = b0; sub1 = b1;
      }
    }
    __syncthreads();
    if (!s_stop){
      int v = (t < curr) ? (int)ndata[t] : -1;
      redv[t] = v; redi[t] = t;
      __syncthreads();
      for (int s = 128; s > 0; s >>= 1){
        if (t < s){
          if (redv[t+s] > redv[t] || (redv[t+s] == redv[t] && redi[t+s] < redi[t])){
            redv[t] = redv[t+s]; redi[t] = redi[t+s];
          }
        }
        __syncthreads();
      }
      if (t == 0) s_m = redi[0];
      __syncthreads();
      redv[t] = (t < curr && ndata[t] == 0u) ? 1 : 0;
      __syncthreads();
      for (int s = 128; s > 0; s >>= 1){
        if (t < s) redv[t] += redv[t+s];
        __syncthreads();
      }
      if (t == 0) s_cnt = redv[0];
      __syncthreads();
      const int m = s_m;
      const int cntE = s_cnt;

      if (t < 64){
        unsigned int nm_ = ndata[m]; if (nm_ < 1u) nm_ = 1u;
        double cd = (double)(long long)sums[m*DIMS + t] * (1.0/1099511627776.0) / (double)nm_;
        cm[t] = (float)cd;
      }
      __syncthreads();

      const int total = curr * DIMS;
      for (int e = t; e < total; e += 256){
        int c = e >> 6, d = e & 63;
        if (c == m) continue;
        float nv;
        unsigned int nd = ndata[c];
        if (nd >= 1u){
          double cd = (double)(long long)sums[e] * (1.0/1099511627776.0) / (double)nd;
          nv = (float)cd;
        } else {
          float rv = jax_normal_elem(sub0, sub1, (uint32_t)e) * 1e-5f;
          nv = cm[d] - rv;
        }
        cb[e] = nv;
      }
      if (t < 64){
        float add = 0.f;
        if (cntE > 0){
          float acc = 0.f;
          for (int c = 0; c < curr; c++){
            if (ndata[c] == 0u)
              acc += jax_normal_elem(sub0, sub1, (uint32_t)(c*DIMS + t)) * 1e-5f;
          }
          add = acc / fmaxf((float)cntE, 1.0f);
        }
        cb[m*DIMS + t] = cm[t] + add;
      }
      __syncthreads();

      for (int c = t; c < curr; c += 256){
        float s = 0.f;
        for (int d = 0; d < DIMS; d++){ float vv = cb[c*DIMS+d]; s += vv*vv; }
        cnorm[c] = s;
      }
      for (int e = t; e < total; e += 256) sums[e] = 0ull;
      for (int c = t; c < curr; c += 256) ndata[c] = 0u;
      if (t == 0) *distacc = 0ull;
    }
  }
  __syncthreads();
  if (n_iter == 4){
    if (curr < 256){
      do_split(cb, cnorm, sums, ndata, distacc, st, curr, next_split, t);
    } else if (t == 0){
      cb[KCB*DIMS] = st->dist;               // finalize: out[16384] = distance
    }
  }
}

extern "C" void kernel_launch(void* const* d_in, const int* in_sizes, int n_in,
                              void* d_out, int out_size, void* d_ws, size_t ws_size,
                              hipStream_t stream){
  const float* x = (const float*)d_in[0];
  float* cb = (float*)d_out;
  char* ws = (char*)d_ws;
  unsigned long long* sums    = (unsigned long long*)(ws + 0);        // 131072 B
  unsigned long long* macc    = (unsigned long long*)(ws + 131072);   // 512 B
  unsigned long long* distacc = (unsigned long long*)(ws + 131584);   // 8 B
  LbgState* st                = (LbgState*)(ws + 131592);             // 24 B
  unsigned int* ndata         = (unsigned int*)(ws + 131616);         // 1024 B
  float* cnorm                = (float*)(ws + 132640);                // 1024 B
  unsigned char* bidx8        = (unsigned char*)(ws + 133664);        // 131072 B
  unsigned int* mcnt          = (unsigned int*)(ws + 264736);         // 4 B

  hipMemsetAsync(d_ws, 0, 264744, stream);
  mean_kernel<<<128, 256, 0, stream>>>(x, macc, cb, cnorm, sums, ndata, distacc, st, mcnt);

  for (int split = 0; split < 8; split++){
    const int curr = 2 << split;
    for (int n = 0; n < 5; n++){
      switch (curr){
        case 2:   estep_kernel<2>  <<<512,256,0,stream>>>(x,cb,cnorm,bidx8,distacc,st);
                  gather_kernel<2,256>   <<<256, 256,0,stream>>>(x,bidx8,sums,ndata,st); break;
        case 4:   estep_kernel<4>  <<<512,256,0,stream>>>(x,cb,cnorm,bidx8,distacc,st);
                  gather_kernel<4,512>   <<<512, 256,0,stream>>>(x,bidx8,sums,ndata,st); break;
        case 8:   estep_kernel<8>  <<<512,256,0,stream>>>(x,cb,cnorm,bidx8,distacc,st);
                  gather_kernel<8,512>   <<<512, 256,0,stream>>>(x,bidx8,sums,ndata,st); break;
        case 16:  estep_kernel<16> <<<512,256,0,stream>>>(x,cb,cnorm,bidx8,distacc,st);
                  gather_kernel<16,512>  <<<512, 256,0,stream>>>(x,bidx8,sums,ndata,st); break;
        case 32:  estep_kernel<32> <<<512,256,0,stream>>>(x,cb,cnorm,bidx8,distacc,st);
                  gather_kernel<32,512>  <<<512, 256,0,stream>>>(x,bidx8,sums,ndata,st); break;
        case 64:  estep_sw<64>   <<<1024,256,0,stream>>>(x,cb,cnorm,bidx8,distacc,st);
                  gather_kernel<64,512>  <<<512, 256,0,stream>>>(x,bidx8,sums,ndata,st); break;
        case 128: estep_sw<128>  <<<1024,256,0,stream>>>(x,cb,cnorm,bidx8,distacc,st);
                  gather_kernel<128,1024><<<1024,256,0,stream>>>(x,bidx8,sums,ndata,st); break;
        case 256: estep_sw<256>  <<<1024,256,0,stream>>>(x,cb,cnorm,bidx8,distacc,st);
                  gather_kernel<256,2048><<<2048,256,0,stream>>>(x,bidx8,sums,ndata,st); break;
      }
      control_kernel<<<1, 256, 0, stream>>>(cb, cnorm, sums, ndata, distacc, st, curr, n, split+1);
    }
  }
}

// Round 14
// 3112.355 us; speedup vs baseline: 5.2445x; 1.0355x over previous
//
#include <hip/hip_runtime.h>
#include <stdint.h>

// LBG vector quantization, bit-faithful port of the JAX ref.
// Round 14: base = R13 (best, 3.22 ms). Changes:
// (a) CURR in {8,16,32} estep -> generalized estep_sw (128-pt LDS tile,
//     1024 blocks = 4/CU = 16 waves/CU vs old 512-block 2-wave-SIMD
//     latency-starved estep_kernel). CURR>=64 instantiation unchanged.
// (b) gather grids: 8:512->1024, 16:512->2048, 32:512->2048 (TLP for
//     latency-bound matched-row loads; NPW>=256 preserved).
// Levels >=64 trajectory bit-identical; 8..32 may flip near-ties
// (absmax stays in the 0.4-0.7 passing class).

#define NPTS 131072
#define DIMS 64
#define KCB  256

struct LbgState { float dist; float prev; unsigned int done; unsigned int k0, k1; unsigned int pad; };

__device__ __forceinline__ uint32_t rotl32(uint32_t v, int n){ return (v<<n)|(v>>(32-n)); }

// Threefry-2x32, 20 rounds (matches jax._src.prng.threefry2x32)
__device__ __forceinline__ void tf2x32(uint32_t k0, uint32_t k1, uint32_t x0, uint32_t x1,
                                       uint32_t& o0, uint32_t& o1){
  uint32_t ks2 = k0 ^ k1 ^ 0x1BD11BDAu;
  x0 += k0; x1 += k1;
  #define TFR(r) { x0 += x1; x1 = rotl32(x1, r); x1 ^= x0; }
  TFR(13) TFR(15) TFR(26) TFR(6)
  x0 += k1; x1 += ks2 + 1u;
  TFR(17) TFR(29) TFR(16) TFR(24)
  x0 += ks2; x1 += k0 + 2u;
  TFR(13) TFR(15) TFR(26) TFR(6)
  x0 += k0; x1 += k1 + 3u;
  TFR(17) TFR(29) TFR(16) TFR(24)
  x0 += k1; x1 += ks2 + 4u;
  TFR(13) TFR(15) TFR(26) TFR(6)
  x0 += ks2; x1 += k0 + 5u;
  #undef TFR
  o0 = x0; o1 = x1;
}

// XLA ErfInv (f32, Giles polynomial)
__device__ __forceinline__ float xla_erfinv_f32(float x){
  float w = -log1pf(-x*x);
  float p;
  if (w < 5.0f){
    w = w - 2.5f;
    p = 2.81022636e-08f;
    p = fmaf(p, w, 3.43273939e-07f);
    p = fmaf(p, w, -3.5233877e-06f);
    p = fmaf(p, w, -4.39150654e-06f);
    p = fmaf(p, w, 0.00021858087f);
    p = fmaf(p, w, -0.00125372503f);
    p = fmaf(p, w, -0.00417768164f);
    p = fmaf(p, w, 0.246640727f);
    p = fmaf(p, w, 1.50140941f);
  } else {
    w = sqrtf(w) - 3.0f;
    p = -0.000200214257f;
    p = fmaf(p, w, 0.000100950558f);
    p = fmaf(p, w, 0.00134934322f);
    p = fmaf(p, w, -0.00367342844f);
    p = fmaf(p, w, 0.00573950773f);
    p = fmaf(p, w, -0.0076224613f);
    p = fmaf(p, w, 0.00943887047f);
    p = fmaf(p, w, 1.00167406f);
    p = fmaf(p, w, 2.83297682f);
  }
  return p * x;
}

__device__ __forceinline__ float jax_normal_elem(uint32_t k0, uint32_t k1, uint32_t j){
  uint32_t o0, o1; tf2x32(k0, k1, 0u, j, o0, o1);
  uint32_t bits = o0 ^ o1;
  uint32_t fb = (bits >> 9) | 0x3f800000u;
  float f = __uint_as_float(fb) - 1.0f;
  const float lo = -0.99999994f;
  float u = f * 2.0f + lo;
  u = fmaxf(lo, u);
  return 1.41421356f * xla_erfinv_f32(u);
}

// --- split phase (used by mean last-block for split0 and control at n==4) ---
__device__ void do_split(float* __restrict__ cb, float* __restrict__ cnorm,
                         unsigned long long* __restrict__ sums,
                         unsigned int* __restrict__ ndata,
                         unsigned long long* __restrict__ distacc,
                         LbgState* __restrict__ st, int curr, int split, int t){
  __shared__ uint32_t kr0s, kr1s;
  if (t == 0){
    uint32_t ks0, ks1, a0, a1, b0, b1;
    tf2x32(0u, 42u, 0u, (uint32_t)split, ks0, ks1);
    tf2x32(ks0, ks1, 0u, 0u, a0, a1);
    tf2x32(ks0, ks1, 0u, 1u, b0, b1);
    kr0s = a0; kr1s = a1;
    st->k0 = b0; st->k1 = b1;
    st->prev = st->dist;
    st->done = 0u;
  }
  __syncthreads();
  const int n = curr * DIMS;
  for (int e = t; e < n; e += 256){
    int c = e >> 6, d = e & 63;
    float rv = jax_normal_elem(kr0s, kr1s, (uint32_t)e) * 1e-5f;
    float old = cb[c*DIMS + d];
    cb[(curr + c)*DIMS + d] = old - rv;
    cb[c*DIMS + d]          = old + rv;
  }
  __syncthreads();
  const int c2 = curr * 2;
  for (int c = t; c < c2; c += 256){
    float s = 0.f;
    for (int d = 0; d < DIMS; d++){ float vv = cb[c*DIMS+d]; s += vv*vv; }
    cnorm[c] = s;
  }
  for (int e = t; e < c2*DIMS; e += 256) sums[e] = 0ull;
  for (int c = t; c < c2; c += 256) ndata[c] = 0u;
  if (t == 0) *distacc = 0ull;
}

// --- mean of x (LDS-tiled) + last block does init + split0 ---
__global__ void mean_kernel(const float* __restrict__ x, unsigned long long* __restrict__ macc,
                            float* __restrict__ cb, float* __restrict__ cnorm,
                            unsigned long long* __restrict__ sums,
                            unsigned int* __restrict__ ndata,
                            unsigned long long* __restrict__ distacc,
                            LbgState* __restrict__ st, unsigned int* __restrict__ mcnt){
  __shared__ double part[256];
  __shared__ float stage[16*64];
  __shared__ int islast;
  const int t = threadIdx.x;
  const int d = t & 63;
  const int w = t >> 6;
  const size_t base = (size_t)blockIdx.x * 1024;
  const int lrow = t >> 4;
  const int lcol = (t & 15) * 4;

  const float4* xg = reinterpret_cast<const float4*>(x);
  float4 nxt = xg[((base + lrow) * DIMS + lcol) >> 2];
  double s = 0.0;
  for (int tt = 0; tt < 64; tt++){
    float4 cur = nxt;
    if (tt < 63)
      nxt = xg[((base + (tt+1)*16 + lrow) * DIMS + lcol) >> 2];
    __syncthreads();
    *reinterpret_cast<float4*>(&stage[lrow*DIMS + lcol]) = cur;
    __syncthreads();
    s += (double)stage[(w    )*DIMS + d];
    s += (double)stage[(w + 4)*DIMS + d];
    s += (double)stage[(w + 8)*DIMS + d];
    s += (double)stage[(w +12)*DIMS + d];
  }
  part[t] = s;
  __syncthreads();
  if (t < 64){
    double tot = part[t] + part[64+t] + part[128+t] + part[192+t];
    atomicAdd(&macc[t], (unsigned long long)__double2ll_rn(tot * 1099511627776.0));
  }
  __threadfence();
  __syncthreads();
  if (t == 0) islast = (atomicAdd(mcnt, 1u) == (unsigned)(gridDim.x - 1));
  __syncthreads();
  if (!islast) return;

  if (t < 64){
    long long mv = (long long)atomicAdd(&macc[t], 0ull);
    double mean = (double)mv * (1.0/1099511627776.0) / 131072.0;
    cb[t] = (float)mean;
  }
  for (int e = t; e < KCB*DIMS; e += 256)
    if (e >= 64) cb[e] = 1e10f;
  if (t == 0){
    st->dist = __builtin_inff();
    st->prev = __builtin_inff();
    st->done = 0u;
    atomicExch(mcnt, 0u);
  }
  __syncthreads();
  do_split(cb, cnorm, sums, ndata, distacc, st, 1, 0, t);
}

// --- E-step for tiny CURR (2,4): one thread per point ---
template<int CURR>
__global__ __launch_bounds__(256, 4)
void estep_kernel(const float* __restrict__ x, const float* __restrict__ cb,
                  const float* __restrict__ cnorm, unsigned char* __restrict__ bidx8,
                  unsigned long long* __restrict__ distacc, const LbgState* __restrict__ st){
  if (st->done) return;
  const int t = threadIdx.x;
  const int lane = t & 63;
  const int p = blockIdx.x * 256 + t;

  float xv[DIMS];
  const float4* xp = reinterpret_cast<const float4*>(x + (size_t)p * DIMS);
  #pragma unroll
  for (int i = 0; i < 16; i++){
    float4 v = xp[i];
    xv[4*i+0] = v.x; xv[4*i+1] = v.y; xv[4*i+2] = v.z; xv[4*i+3] = v.w;
  }
  float xx = 0.f;
  #pragma unroll
  for (int d = 0; d < DIMS; d++) xx += xv[d] * xv[d];

  constexpr int NJ = (CURR < 4) ? CURR : 4;
  float best = __builtin_inff();
  int bi = 0;
  for (int j0 = 0; j0 < CURR; j0 += NJ){
    const float* crow = cb + (size_t)j0 * DIMS;
    float acc[NJ];
    #pragma unroll
    for (int k = 0; k < NJ; k++) acc[k] = 0.f;
    #pragma unroll
    for (int d = 0; d < DIMS; d++){
      #pragma unroll
      for (int k = 0; k < NJ; k++)
        acc[k] = fmaf(xv[d], crow[k*DIMS + d], acc[k]);
    }
    #pragma unroll
    for (int k = 0; k < NJ; k++){
      float d2 = (xx - 2.0f*acc[k]) + cnorm[j0 + k];
      if (d2 < best){ best = d2; bi = j0 + k; }
    }
  }
  bidx8[p] = (unsigned char)bi;

  double dd = 0.0;
  const float4* cbv = reinterpret_cast<const float4*>(cb + (size_t)bi * DIMS);
  #pragma unroll
  for (int i = 0; i < 16; i++){
    float4 b = cbv[i];
    float df, sq;
    df = xv[4*i+0] - b.x; sq = df*df; dd += (double)sq;
    df = xv[4*i+1] - b.y; sq = df*df; dd += (double)sq;
    df = xv[4*i+2] - b.z; sq = df*df; dd += (double)sq;
    df = xv[4*i+3] - b.w; sq = df*df; dd += (double)sq;
  }
  for (int off = 32; off > 0; off >>= 1) dd += __shfl_down(dd, off);
  if (lane == 0)
    atomicAdd(distacc, (unsigned long long)__double2ll_rn(dd * 4294967296.0));
}

// --- E-step CURR>=8 "scalar-wave": wave w owns uniform CURR/4 cw stripe ->
// cb/cnorm via s_load; thread = 2 points; LDS = x tile (4 blocks/CU).
// For CURR>=64 identical to R13 (bit-identical). Group size = min(CPW,8).
template<int CURR>
__global__ __launch_bounds__(256, 4)
void estep_sw(const float* __restrict__ x, const float* __restrict__ cb,
              const float* __restrict__ cnorm, unsigned char* __restrict__ bidx8,
              unsigned long long* __restrict__ distacc, const LbgState* __restrict__ st){
  if (st->done) return;
  constexpr int CPW = CURR / 4;              // codewords per wave (>=2)
  constexpr int NJG = (CPW < 8) ? CPW : 8;   // cw-group size
  constexpr int NG = CPW / NJG;              // groups per wave
  __shared__ float4 xs[16*128];              // 32 KB
  __shared__ float sxx[128];
  __shared__ float sbest[4*128];
  __shared__ int   sidx [4*128];
  __shared__ unsigned char sbidx[128];
  const int t = threadIdx.x;
  const int lane = t & 63;
  const int w = __builtin_amdgcn_readfirstlane(t >> 6);
  const int pbase = blockIdx.x * 128;

  { // stage x tile k-major
    const int p = t & 127, h = t >> 7;
    const float4* xg = reinterpret_cast<const float4*>(x) + (size_t)(pbase + p) * 16 + h * 8;
    #pragma unroll
    for (int j = 0; j < 8; j++)
      xs[(h*8 + j)*128 + p] = xg[j];
  }
  __syncthreads();
  if (t < 128){
    float xx = 0.f;
    #pragma unroll
    for (int k4 = 0; k4 < 16; k4++){
      float4 v = xs[k4*128 + t];
      xx = fmaf(v.x, v.x, xx); xx = fmaf(v.y, v.y, xx);
      xx = fmaf(v.z, v.z, xx); xx = fmaf(v.w, v.w, xx);
    }
    sxx[t] = xx;
  }
  __syncthreads();

  const float xx0 = sxx[lane];
  const float xx1 = sxx[64 + lane];
  float best0 = __builtin_inff(), best1 = __builtin_inff();
  int bi0 = 0, bi1 = 0;
  const float4* cbg = reinterpret_cast<const float4*>(cb);
  const int cwbase = w * CPW;

  for (int g = 0; g < NG; g++){
    const int c0 = cwbase + g*NJG;
    float acc0[NJG], acc1[NJG];
    #pragma unroll
    for (int cj = 0; cj < NJG; cj++){ acc0[cj] = 0.f; acc1[cj] = 0.f; }
    for (int k4 = 0; k4 < 16; k4++){
      float4 xf0 = xs[k4*128 + lane];
      float4 xf1 = xs[k4*128 + 64 + lane];
      #pragma unroll
      for (int cj = 0; cj < NJG; cj++){
        float4 cf = cbg[(size_t)(c0 + cj)*16 + k4];   // wave-uniform -> s_load
        acc0[cj] = fmaf(xf0.x, cf.x, acc0[cj]);
        acc0[cj] = fmaf(xf0.y, cf.y, acc0[cj]);
        acc0[cj] = fmaf(xf0.z, cf.z, acc0[cj]);
        acc0[cj] = fmaf(xf0.w, cf.w, acc0[cj]);
        acc1[cj] = fmaf(xf1.x, cf.x, acc1[cj]);
        acc1[cj] = fmaf(xf1.y, cf.y, acc1[cj]);
        acc1[cj] = fmaf(xf1.z, cf.z, acc1[cj]);
        acc1[cj] = fmaf(xf1.w, cf.w, acc1[cj]);
      }
    }
    #pragma unroll
    for (int cj = 0; cj < NJG; cj++){
      float cn = cnorm[c0 + cj];                      // wave-uniform -> s_load
      float d20 = (xx0 - 2.0f*acc0[cj]) + cn;
      if (d20 < best0){ best0 = d20; bi0 = c0 + cj; } // ascending c within wave
      float d21 = (xx1 - 2.0f*acc1[cj]) + cn;
      if (d21 < best1){ best1 = d21; bi1 = c0 + cj; }
    }
  }
  sbest[w*128 + lane]      = best0;  sidx[w*128 + lane]      = bi0;
  sbest[w*128 + 64 + lane] = best1;  sidx[w*128 + 64 + lane] = bi1;
  __syncthreads();

  if (t < 128){
    float best = sbest[t];
    int bi = sidx[t];
    #pragma unroll
    for (int ww = 1; ww < 4; ww++){                   // ascending cw ranges
      float ob = sbest[ww*128 + t];
      int   oi = sidx [ww*128 + t];
      if (ob < best){ best = ob; bi = oi; }           // strict < keeps lowest
    }
    sbidx[t] = (unsigned char)bi;
    bidx8[pbase + t] = (unsigned char)bi;
    const float4* cbv = cbg + (size_t)bi * 16;
    double dd = 0.0;
    #pragma unroll
    for (int k4 = 0; k4 < 16; k4++){
      float4 xv = xs[k4*128 + t];
      float4 b = cbv[k4];
      float df, sq;
      df = xv.x - b.x; sq = df*df; dd += (double)sq;
      df = xv.y - b.y; sq = df*df; dd += (double)sq;
      df = xv.z - b.z; sq = df*df; dd += (double)sq;
      df = xv.w - b.w; sq = df*df; dd += (double)sq;
    }
    for (int off = 32; off > 0; off >>= 1) dd += __shfl_down(dd, off);
    if ((t & 63) == 0)
      atomicAdd(distacc, (unsigned long long)__double2ll_rn(dd * 4294967296.0));
  }
}

// --- Gather (R8): ballot-harvest with 4-deep load queue ---
template<int CURR, int NBLK>
__global__ __launch_bounds__(256)
void gather_kernel(const float* __restrict__ x, const unsigned char* __restrict__ bidx8,
                   unsigned long long* __restrict__ sums, unsigned int* __restrict__ ndata,
                   const LbgState* __restrict__ st){
  if (st->done) return;
  constexpr int CLOG = __builtin_ctz(CURR);
  constexpr int NCHUNK = NBLK / CURR;
  constexpr int PPC = NPTS / NCHUNK;
  constexpr int NPW = PPC / 4;
  __shared__ long long sacc[4*64];
  __shared__ unsigned int scw[4];
  const int t = threadIdx.x;
  const int lane = t & 63;
  const int w = t >> 6;
  const int c = blockIdx.x & (CURR - 1);
  const int chunk = blockIdx.x >> CLOG;
  const int pbase = chunk * PPC + w * NPW;

  long long acc = 0;
  unsigned int cnt = 0;
  int q0 = 0, q1 = 0, q2 = 0, q3 = 0, qn = 0;
  const uint32_t* bp = reinterpret_cast<const uint32_t*>(bidx8 + pbase);
  for (int i = 0; i < NPW; i += 256){
    const uint32_t b4 = bp[(i >> 2) + lane];
    #pragma unroll
    for (int s = 0; s < 4; s++){
      unsigned long long m = __ballot(((b4 >> (8*s)) & 255u) == (unsigned)c);
      cnt += (unsigned int)__popcll(m);
      while (m){
        const int bit = __builtin_ctzll(m);
        m &= m - 1ull;
        const int p = pbase + i + bit*4 + s;
        if      (qn == 0) q0 = p;
        else if (qn == 1) q1 = p;
        else if (qn == 2) q2 = p;
        else              q3 = p;
        qn++;
        if (qn == 4){
          const float v0 = x[(size_t)q0 * DIMS + lane];
          const float v1 = x[(size_t)q1 * DIMS + lane];
          const float v2 = x[(size_t)q2 * DIMS + lane];
          const float v3 = x[(size_t)q3 * DIMS + lane];
          acc += (long long)__double2int_rn((double)v0 * 1048576.0);
          acc += (long long)__double2int_rn((double)v1 * 1048576.0);
          acc += (long long)__double2int_rn((double)v2 * 1048576.0);
          acc += (long long)__double2int_rn((double)v3 * 1048576.0);
          qn = 0;
        }
      }
    }
  }
  if (qn > 0){
    const int i1 = (qn > 1) ? q1 : q0;
    const int i2 = (qn > 2) ? q2 : q0;
    const float v0 = x[(size_t)q0 * DIMS + lane];
    const float v1 = x[(size_t)i1 * DIMS + lane];
    const float v2 = x[(size_t)i2 * DIMS + lane];
    acc += (long long)__double2int_rn((double)v0 * 1048576.0);
    if (qn > 1) acc += (long long)__double2int_rn((double)v1 * 1048576.0);
    if (qn > 2) acc += (long long)__double2int_rn((double)v2 * 1048576.0);
  }
  sacc[w*64 + lane] = acc;
  if (lane == 0) scw[w] = cnt;
  __syncthreads();
  if (w == 0){
    long long tot = sacc[lane] + sacc[64+lane] + sacc[128+lane] + sacc[192+lane];
    if (tot) atomicAdd(&sums[c*DIMS + lane], (unsigned long long)(tot * 1048576ll));
    if (lane == 0){
      unsigned int ct = scw[0] + scw[1] + scw[2] + scw[3];
      if (ct) atomicAdd(&ndata[c], ct);
    }
  }
}

// --- convergence + M-step finalize + (n==4) split/finalize (one block) ---
__global__ void control_kernel(float* __restrict__ cb, float* __restrict__ cnorm,
                               unsigned long long* __restrict__ sums,
                               unsigned int* __restrict__ ndata,
                               unsigned long long* __restrict__ distacc,
                               LbgState* __restrict__ st, int curr, int n_iter,
                               int next_split){
  __shared__ int s_stop;
  __shared__ unsigned int sdone;
  __shared__ uint32_t sub0, sub1;
  __shared__ float cm[64];
  __shared__ int redv[256];
  __shared__ int redi[256];
  __shared__ int s_m, s_cnt;
  const int t = threadIdx.x;
  if (t == 0) sdone = st->done;
  __syncthreads();
  const unsigned int done0 = sdone;

  if (!done0){
    if (t == 0){
      double dd = (double)(long long)(*distacc) * (1.0/4294967296.0);
      float sf = (float)dd;
      float d_new = sf / 131072.0f;
      float change = fabsf(st->prev - d_new);
      int conv = (n_iter > 0) && (change / (d_new + 1e-16f) < 1e-5f);
      st->dist = d_new;
      if (!conv) st->prev = d_new;
      st->done = conv ? 1u : 0u;
      s_stop = conv;
      if (!conv){
        uint32_t a0, a1, b0, b1;
        tf2x32(st->k0, st->k1, 0u, 0u, a0, a1);
        tf2x32(st->k0, st->k1, 0u, 1u, b0, b1);
        st->k0 = a0; st->k1 = a1;
        sub0 = b0; sub1 = b1;
      }
    }
    __syncthreads();
    if (!s_stop){
      int v = (t < curr) ? (int)ndata[t] : -1;
      redv[t] = v; redi[t] = t;
      __syncthreads();
      for (int s = 128; s > 0; s >>= 1){
        if (t < s){
          if (redv[t+s] > redv[t] || (redv[t+s] == redv[t] && redi[t+s] < redi[t])){
            redv[t] = redv[t+s]; redi[t] = redi[t+s];
          }
        }
        __syncthreads();
      }
      if (t == 0) s_m = redi[0];
      __syncthreads();
      redv[t] = (t < curr && ndata[t] == 0u) ? 1 : 0;
      __syncthreads();
      for (int s = 128; s > 0; s >>= 1){
        if (t < s) redv[t] += redv[t+s];
        __syncthreads();
      }
      if (t == 0) s_cnt = redv[0];
      __syncthreads();
      const int m = s_m;
      const int cntE = s_cnt;

      if (t < 64){
        unsigned int nm_ = ndata[m]; if (nm_ < 1u) nm_ = 1u;
        double cd = (double)(long long)sums[m*DIMS + t] * (1.0/1099511627776.0) / (double)nm_;
        cm[t] = (float)cd;
      }
      __syncthreads();

      const int total = curr * DIMS;
      for (int e = t; e < total; e += 256){
        int c = e >> 6, d = e & 63;
        if (c == m) continue;
        float nv;
        unsigned int nd = ndata[c];
        if (nd >= 1u){
          double cd = (double)(long long)sums[e] * (1.0/1099511627776.0) / (double)nd;
          nv = (float)cd;
        } else {
          float rv = jax_normal_elem(sub0, sub1, (uint32_t)e) * 1e-5f;
          nv = cm[d] - rv;
        }
        cb[e] = nv;
      }
      if (t < 64){
        float add = 0.f;
        if (cntE > 0){
          float acc = 0.f;
          for (int c = 0; c < curr; c++){
            if (ndata[c] == 0u)
              acc += jax_normal_elem(sub0, sub1, (uint32_t)(c*DIMS + t)) * 1e-5f;
          }
          add = acc / fmaxf((float)cntE, 1.0f);
        }
        cb[m*DIMS + t] = cm[t] + add;
      }
      __syncthreads();

      for (int c = t; c < curr; c += 256){
        float s = 0.f;
        for (int d = 0; d < DIMS; d++){ float vv = cb[c*DIMS+d]; s += vv*vv; }
        cnorm[c] = s;
      }
      for (int e = t; e < total; e += 256) sums[e] = 0ull;
      for (int c = t; c < curr; c += 256) ndata[c] = 0u;
      if (t == 0) *distacc = 0ull;
    }
  }
  __syncthreads();
  if (n_iter == 4){
    if (curr < 256){
      do_split(cb, cnorm, sums, ndata, distacc, st, curr, next_split, t);
    } else if (t == 0){
      cb[KCB*DIMS] = st->dist;               // finalize: out[16384] = distance
    }
  }
}

extern "C" void kernel_launch(void* const* d_in, const int* in_sizes, int n_in,
                              void* d_out, int out_size, void* d_ws, size_t ws_size,
                              hipStream_t stream){
  const float* x = (const float*)d_in[0];
  float* cb = (float*)d_out;
  char* ws = (char*)d_ws;
  unsigned long long* sums    = (unsigned long long*)(ws + 0);        // 131072 B
  unsigned long long* macc    = (unsigned long long*)(ws + 131072);   // 512 B
  unsigned long long* distacc = (unsigned long long*)(ws + 131584);   // 8 B
  LbgState* st                = (LbgState*)(ws + 131592);             // 24 B
  unsigned int* ndata         = (unsigned int*)(ws + 131616);         // 1024 B
  float* cnorm                = (float*)(ws + 132640);                // 1024 B
  unsigned char* bidx8        = (unsigned char*)(ws + 133664);        // 131072 B
  unsigned int* mcnt          = (unsigned int*)(ws + 264736);         // 4 B

  hipMemsetAsync(d_ws, 0, 264744, stream);
  mean_kernel<<<128, 256, 0, stream>>>(x, macc, cb, cnorm, sums, ndata, distacc, st, mcnt);

  for (int split = 0; split < 8; split++){
    const int curr = 2 << split;
    for (int n = 0; n < 5; n++){
      switch (curr){
        case 2:   estep_kernel<2>  <<<512,256,0,stream>>>(x,cb,cnorm,bidx8,distacc,st);
                  gather_kernel<2,256>   <<<256, 256,0,stream>>>(x,bidx8,sums,ndata,st); break;
        case 4:   estep_kernel<4>  <<<512,256,0,stream>>>(x,cb,cnorm,bidx8,distacc,st);
                  gather_kernel<4,512>   <<<512, 256,0,stream>>>(x,bidx8,sums,ndata,st); break;
        case 8:   estep_sw<8>    <<<1024,256,0,stream>>>(x,cb,cnorm,bidx8,distacc,st);
                  gather_kernel<8,1024>  <<<1024,256,0,stream>>>(x,bidx8,sums,ndata,st); break;
        case 16:  estep_sw<16>   <<<1024,256,0,stream>>>(x,cb,cnorm,bidx8,distacc,st);
                  gather_kernel<16,2048> <<<2048,256,0,stream>>>(x,bidx8,sums,ndata,st); break;
        case 32:  estep_sw<32>   <<<1024,256,0,stream>>>(x,cb,cnorm,bidx8,distacc,st);
                  gather_kernel<32,2048> <<<2048,256,0,stream>>>(x,bidx8,sums,ndata,st); break;
        case 64:  estep_sw<64>   <<<1024,256,0,stream>>>(x,cb,cnorm,bidx8,distacc,st);
                  gather_kernel<64,512>  <<<512, 256,0,stream>>>(x,bidx8,sums,ndata,st); break;
        case 128: estep_sw<128>  <<<1024,256,0,stream>>>(x,cb,cnorm,bidx8,distacc,st);
                  gather_kernel<128,1024><<<1024,256,0,stream>>>(x,bidx8,sums,ndata,st); break;
        case 256: estep_sw<256>  <<<1024,256,0,stream>>>(x,cb,cnorm,bidx8,distacc,st);
                  gather_kernel<256,2048><<<2048,256,0,stream>>>(x,bidx8,sums,ndata,st); break;
      }
      control_kernel<<<1, 256, 0, stream>>>(cb, cnorm, sums, ndata, distacc, st, curr, n, split+1);
    }
  }
}